// Round 1
// baseline (917.414 us; speedup 1.0000x reference)
//
#include <hip/hip_runtime.h>

#define NB 32
#define L 1024
#define H 1024

typedef __attribute__((ext_vector_type(4))) float floatx4;
typedef __attribute__((ext_vector_type(8))) short shortx8;
typedef __attribute__((ext_vector_type(8))) unsigned short ushortx8;

__device__ __forceinline__ unsigned short f2bf(float f) {
    union { float f; unsigned int u; } v; v.f = f;
    unsigned int u = v.u;
    u += 0x7fffu + ((u >> 16) & 1u);   // round-to-nearest-even
    return (unsigned short)(u >> 16);
}
__device__ __forceinline__ float bf2f(unsigned short h) {
    union { unsigned int u; float f; } v; v.u = ((unsigned int)h) << 16;
    return v.f;
}

// async global->LDS, 16B per lane. Dest must be wave-uniform base + lane*16.
__device__ __forceinline__ void gload_lds16(const void* g, void* l) {
    __builtin_amdgcn_global_load_lds(
        (const __attribute__((address_space(1))) unsigned int*)g,
        (__attribute__((address_space(3))) unsigned int*)l, 16, 0, 0);
}

// ---- dtype detection: bf16 vs fp32 materialization of the float tensors ----
__global__ void detect_kernel(const unsigned short* a, int* flag) {
    int tid = threadIdx.x;
    unsigned short u = a[tid];
    int e = (u >> 7) & 0xff;
    int ok = (u == 0) || (e >= 116 && e <= 136);
    unsigned long long ball = __ballot(ok != 0);
    if (tid == 0) flag[0] = (__popcll(ball) >= 56) ? 1 : 0;
}

__device__ __forceinline__ void store_out(void* out, size_t eidx, float v, int isbf) {
    if (isbf) ((unsigned short*)out)[eidx] = f2bf(v);
    else      ((float*)out)[eidx] = v;
}

// Convert a,b slices to bf16 (contiguous a_c/b_c AND transposed aT/bT) and
// accumulate per-(b,h) column sums into mean accumulators (zeroed by memset).
// grid: (H/64, L/64, nb*2); block 256.
__global__ __launch_bounds__(256) void convT_kernel(
    const void* A, const void* Bm, const int* flag,
    unsigned short* a_c, unsigned short* b_c,
    unsigned short* aT, unsigned short* bT,
    float* mean_a, float* mean_b, int b0) {
    __shared__ __align__(16) unsigned short T[64][80];
    int z = blockIdx.z;
    int which = z & 1, bi_l = z >> 1, bi = b0 + bi_l;
    int s0 = blockIdx.y * 64, h0 = blockIdx.x * 64;
    const void* src = which ? Bm : A;
    unsigned short* xc = which ? b_c : a_c;
    unsigned short* xT = which ? bT : aT;
    float* msum = which ? mean_b : mean_a;
    int isbf = flag[0];
    int tid = threadIdx.x;

    int r = tid >> 2, c0 = (tid & 3) * 16;
    size_t gin = (size_t)bi * L * H + (size_t)(s0 + r) * H + h0 + c0;
    unsigned short v[16];
    if (isbf) {
        const unsigned short* p = (const unsigned short*)src + gin;
        *(ushortx8*)&v[0] = *(const ushortx8*)p;
        *(ushortx8*)&v[8] = *(const ushortx8*)(p + 8);
    } else {
        const float* p = (const float*)src + gin;
#pragma unroll
        for (int u = 0; u < 16; u += 4) {
            float4 f = *(const float4*)(p + u);
            v[u] = f2bf(f.x); v[u + 1] = f2bf(f.y);
            v[u + 2] = f2bf(f.z); v[u + 3] = f2bf(f.w);
        }
    }
    *(ushortx8*)&T[r][c0] = *(const ushortx8*)&v[0];
    *(ushortx8*)&T[r][c0 + 8] = *(const ushortx8*)&v[8];
    size_t gco = (size_t)bi_l * L * H + (size_t)(s0 + r) * H + h0 + c0;
    *(ushortx8*)&xc[gco] = *(const ushortx8*)&v[0];
    *(ushortx8*)&xc[gco + 8] = *(const ushortx8*)&v[8];
    __syncthreads();

    int hr = tid >> 2, sc0 = (tid & 3) * 16;
    unsigned short tv2[16];
    float ms = 0.f;
#pragma unroll
    for (int u = 0; u < 16; ++u) {
        unsigned short q = T[sc0 + u][hr];
        tv2[u] = q;
        ms += bf2f(q);
    }
    size_t gto = (size_t)bi_l * (size_t)H * L + (size_t)(h0 + hr) * L + s0 + sc0;
    *(ushortx8*)&xT[gto] = *(const ushortx8*)&tv2[0];
    *(ushortx8*)&xT[gto + 8] = *(const ushortx8*)&tv2[8];
    // reduce the 4 lanes sharing hr, then one atomic per (h)
    ms += __shfl_xor(ms, 1);
    ms += __shfl_xor(ms, 2);
    if ((tid & 3) == 0) atomicAdd(&msum[bi * H + h0 + hr], ms);
}

// 64x64 bf16 tile transpose: wT[t][s] = w[s][t]. grid (16,16,nb); block 256.
__global__ __launch_bounds__(256) void wtrans_kernel(const unsigned short* w,
                                                     unsigned short* wT) {
    __shared__ __align__(16) unsigned short T[64][80];
    int bi_l = blockIdx.z;
    int s0 = blockIdx.y * 64, t0 = blockIdx.x * 64;
    int tid = threadIdx.x;
    int r = tid >> 2, c0 = (tid & 3) * 16;
    size_t gin = (size_t)bi_l * L * L + (size_t)(s0 + r) * L + t0 + c0;
    *(ushortx8*)&T[r][c0] = *(const ushortx8*)&w[gin];
    *(ushortx8*)&T[r][c0 + 8] = *(const ushortx8*)&w[gin + 8];
    __syncthreads();
    int tr = tid >> 2, sc0 = (tid & 3) * 16;
    unsigned short o[16];
#pragma unroll
    for (int u = 0; u < 16; ++u) o[u] = T[sc0 + u][tr];
    size_t gout = (size_t)bi_l * L * L + (size_t)(t0 + tr) * L + s0 + sc0;
    *(ushortx8*)&wT[gout] = *(const ushortx8*)&o[0];
    *(ushortx8*)&wT[gout + 8] = *(const ushortx8*)&o[8];
}

// m97-structure K-loop: C(128x128) += A(128xK) * B(128xK)^T, both operands
// k-contiguous bf16 rows. LDS [128][32] u16 unpadded (global_load_lds needs
// linear dest). 2 barriers / K-step.
__device__ __forceinline__ void gemm_kk(
    const unsigned short* Arow, const unsigned short* Brow,
    int lda, int ldb, int K,
    unsigned short* AsBase, unsigned short* BsBase,
    int tid, floatx4 (&acc)[4][4]) {
    int lane = tid & 63;
    int wid = tid >> 6;
    int wm = wid >> 1, wn = wid & 1;
    int lane15 = lane & 15, quad = lane >> 4;

    for (int k0 = 0; k0 < K; k0 += 32) {
#pragma unroll
        for (int it = 0; it < 4; ++it) {
            int idx = (it & 1) * 256 + tid;       // 0..511
            int rr = idx >> 2, cc = (idx & 3) * 8;
            const unsigned short* src = (it < 2)
                ? (Arow + (size_t)rr * lda + k0 + cc)
                : (Brow + (size_t)rr * ldb + k0 + cc);
            unsigned short* dst = ((it < 2) ? AsBase : BsBase) + idx * 8;
            gload_lds16(src, dst);
        }
        __syncthreads();
        shortx8 af[4], bfr[4];
#pragma unroll
        for (int i = 0; i < 4; ++i)
            af[i] = *(const shortx8*)(AsBase + (wm * 64 + i * 16 + lane15) * 32 + quad * 8);
#pragma unroll
        for (int j = 0; j < 4; ++j)
            bfr[j] = *(const shortx8*)(BsBase + (wn * 64 + j * 16 + lane15) * 32 + quad * 8);
#pragma unroll
        for (int i = 0; i < 4; ++i)
#pragma unroll
            for (int j = 0; j < 4; ++j)
                acc[i][j] = __builtin_amdgcn_mfma_f32_16x16x32_bf16(af[i], bfr[j], acc[i][j], 0, 0, 0);
        __syncthreads();
    }
}

// S = a_c . b_c^T * tau; w = mask ? exp(S) : 0 (bf16). Fused row/col sums
// (shuffle-reduce + atomics into zeroed row_l/col_l).
__global__ __launch_bounds__(256) void score_kernel(
    const unsigned short* a_c, const unsigned short* b_c,
    const int* mask_a, const int* mask_b, const void* temp, const int* flag,
    unsigned short* w, float* row_l, float* col_l, int b0) {
    __shared__ __align__(16) unsigned short As[128 * 32];
    __shared__ __align__(16) unsigned short Bs[128 * 32];
    int bi_l = blockIdx.z, bi = b0 + bi_l;
    int s0 = blockIdx.y * 128, t0 = blockIdx.x * 128;
    int tid = threadIdx.x;

    floatx4 acc[4][4];
#pragma unroll
    for (int i = 0; i < 4; ++i)
#pragma unroll
        for (int j = 0; j < 4; ++j)
#pragma unroll
            for (int rr = 0; rr < 4; ++rr) acc[i][j][rr] = 0.f;

    gemm_kk(a_c + (size_t)bi_l * L * H + (size_t)s0 * H,
            b_c + (size_t)bi_l * L * H + (size_t)t0 * H,
            H, H, H, As, Bs, tid, acc);

    int isbf = flag[0];
    float tv = isbf ? bf2f(((const unsigned short*)temp)[0]) : ((const float*)temp)[0];
    int lane = tid & 63, wid = tid >> 6;
    int wm = wid >> 1, wn = wid & 1;
    int lane15 = lane & 15, quad = lane >> 4;

    int mb[4];
#pragma unroll
    for (int j = 0; j < 4; ++j)
        mb[j] = mask_b[bi * L + t0 + wn * 64 + j * 16 + lane15];
    size_t wbase = (size_t)bi_l * L * L;
    float colp[4] = {0.f, 0.f, 0.f, 0.f};
#pragma unroll
    for (int i = 0; i < 4; ++i) {
#pragma unroll
        for (int r = 0; r < 4; ++r) {
            int s = s0 + wm * 64 + i * 16 + quad * 4 + r;
            int ma = mask_a[bi * L + s];
            float rp = 0.f;
#pragma unroll
            for (int j = 0; j < 4; ++j) {
                int t = t0 + wn * 64 + j * 16 + lane15;
                float wv = (ma && mb[j]) ? __expf(acc[i][j][r] * tv) : 0.f;
                unsigned short wq = f2bf(wv);
                w[wbase + (size_t)s * L + t] = wq;
                float wf = bf2f(wq);       // sum exactly what we stored
                rp += wf;
                colp[j] += wf;
            }
            rp += __shfl_xor(rp, 1);
            rp += __shfl_xor(rp, 2);
            rp += __shfl_xor(rp, 4);
            rp += __shfl_xor(rp, 8);
            if (lane15 == 0) atomicAdd(&row_l[bi * L + s], rp);
        }
    }
#pragma unroll
    for (int j = 0; j < 4; ++j) {
        float cp = colp[j];
        cp += __shfl_xor(cp, 16);
        cp += __shfl_xor(cp, 32);
        if (quad == 0) {
            int t = t0 + wn * 64 + j * 16 + lane15;
            atomicAdd(&col_l[bi * L + t], cp);
        }
    }
}

// feature_a[s,h] = ma ? (sum_t w[s,t] b[t,h]) / row_l[s] : mean_b[h]
__global__ __launch_bounds__(256) void feat_a_kernel(
    const unsigned short* w, const unsigned short* bT, const int* mask_a,
    const int* flag, const float* row_l, const float* mean_b, void* out, int b0) {
    __shared__ __align__(16) unsigned short As[128 * 32];
    __shared__ __align__(16) unsigned short Bs[128 * 32];
    int bi_l = blockIdx.z, bi = b0 + bi_l;
    int s0 = blockIdx.y * 128, h0 = blockIdx.x * 128;
    int tid = threadIdx.x;

    floatx4 acc[4][4];
#pragma unroll
    for (int i = 0; i < 4; ++i)
#pragma unroll
        for (int j = 0; j < 4; ++j)
#pragma unroll
            for (int rr = 0; rr < 4; ++rr) acc[i][j][rr] = 0.f;

    gemm_kk(w + (size_t)bi_l * L * L + (size_t)s0 * L,
            bT + (size_t)bi_l * (size_t)H * L + (size_t)h0 * L,
            L, L, L, As, Bs, tid, acc);

    int isbf = flag[0];
    int lane = tid & 63, wid = tid >> 6;
    int wm = wid >> 1, wn = wid & 1;
    int lane15 = lane & 15, quad = lane >> 4;
    const float invL = 1.f / (float)L;
#pragma unroll
    for (int i = 0; i < 4; ++i) {
#pragma unroll
        for (int r = 0; r < 4; ++r) {
            int s = s0 + wm * 64 + i * 16 + quad * 4 + r;
            int ma = mask_a[bi * L + s];
            float scale = ma ? (1.f / row_l[bi * L + s]) : 0.f;
#pragma unroll
            for (int j = 0; j < 4; ++j) {
                int h = h0 + wn * 64 + j * 16 + lane15;
                float v = ma ? acc[i][j][r] * scale : mean_b[bi * H + h] * invL;
                store_out(out, (size_t)bi * L * H + (size_t)s * H + h, v, isbf);
            }
        }
    }
}

// feature_b[t,h] = mb ? (sum_s w[s,t] a[s,h]) / col_l[t] : mean_a[h]
__global__ __launch_bounds__(256) void feat_b_kernel(
    const unsigned short* wT, const unsigned short* aT, const int* mask_b,
    const int* flag, const float* col_l, const float* mean_a, void* out, int b0) {
    __shared__ __align__(16) unsigned short As[128 * 32];
    __shared__ __align__(16) unsigned short Bs[128 * 32];
    int bi_l = blockIdx.z, bi = b0 + bi_l;
    int t0 = blockIdx.y * 128, h0 = blockIdx.x * 128;
    int tid = threadIdx.x;

    floatx4 acc[4][4];
#pragma unroll
    for (int i = 0; i < 4; ++i)
#pragma unroll
        for (int j = 0; j < 4; ++j)
#pragma unroll
            for (int rr = 0; rr < 4; ++rr) acc[i][j][rr] = 0.f;

    gemm_kk(wT + (size_t)bi_l * L * L + (size_t)t0 * L,
            aT + (size_t)bi_l * (size_t)H * L + (size_t)h0 * L,
            L, L, L, As, Bs, tid, acc);

    int isbf = flag[0];
    int lane = tid & 63, wid = tid >> 6;
    int wm = wid >> 1, wn = wid & 1;
    int lane15 = lane & 15, quad = lane >> 4;
    const float invL = 1.f / (float)L;
    const size_t FEAT_B_OFF = (size_t)NB * L * H;
#pragma unroll
    for (int i = 0; i < 4; ++i) {
#pragma unroll
        for (int r = 0; r < 4; ++r) {
            int t = t0 + wm * 64 + i * 16 + quad * 4 + r;
            int mbv = mask_b[bi * L + t];
            float scale = mbv ? (1.f / col_l[bi * L + t]) : 0.f;
#pragma unroll
            for (int j = 0; j < 4; ++j) {
                int h = h0 + wn * 64 + j * 16 + lane15;
                float v = mbv ? acc[i][j][r] * scale : mean_a[bi * H + h] * invL;
                store_out(out, FEAT_B_OFF + (size_t)bi * L * H + (size_t)t * H + h, v, isbf);
            }
        }
    }
}

extern "C" void kernel_launch(void* const* d_in, const int* in_sizes, int n_in,
                              void* d_out, int out_size, void* d_ws, size_t ws_size,
                              hipStream_t stream) {
    const void* a = d_in[0];
    const void* b = d_in[1];
    const int* mask_a = (const int*)d_in[2];
    const int* mask_b = (const int*)d_in[3];
    const void* temp = d_in[4];

    // Workspace: stats first (zeroed), then 6 chunk-sized bf16 buffers.
    char* wsp = (char*)d_ws;
    float* row_l  = (float*)wsp;                       // NB*L
    float* col_l  = row_l + (size_t)NB * L;            // NB*L
    float* mean_a = col_l + (size_t)NB * L;            // NB*H (raw sums)
    float* mean_b = mean_a + (size_t)NB * H;           // NB*H (raw sums)
    int*   flag   = (int*)(mean_b + (size_t)NB * H);
    const size_t stats_bytes = ((size_t)NB * L * 2 + (size_t)NB * H * 2) * 4 + 256;

    const size_t per_batch = 6 * (size_t)L * H * 2;    // a_c,b_c,aT,bT,w,wT = 12 MiB
    size_t wavail = (ws_size > stats_bytes) ? ws_size - stats_bytes : 0;
    int chunk = (int)(wavail / per_batch);
    if (chunk < 1) chunk = 1;
    if (chunk > NB) chunk = NB;

    unsigned short* a_c  = (unsigned short*)(wsp + stats_bytes);
    unsigned short* b_c  = a_c + (size_t)chunk * L * H;
    unsigned short* aT   = b_c + (size_t)chunk * L * H;
    unsigned short* bT   = aT  + (size_t)chunk * L * H;
    unsigned short* wbuf = bT  + (size_t)chunk * L * H;
    unsigned short* wT   = wbuf + (size_t)chunk * L * L;

    hipMemsetAsync(d_ws, 0, stats_bytes, stream);      // zero row/col/mean accums
    detect_kernel<<<1, 64, 0, stream>>>((const unsigned short*)a, flag);

    for (int b0 = 0; b0 < NB; b0 += chunk) {
        int nb = (NB - b0 < chunk) ? (NB - b0) : chunk;
        convT_kernel<<<dim3(16, 16, nb * 2), 256, 0, stream>>>(
            a, b, flag, a_c, b_c, aT, bT, mean_a, mean_b, b0);
        score_kernel<<<dim3(8, 8, nb), 256, 0, stream>>>(
            a_c, b_c, mask_a, mask_b, temp, flag, wbuf, row_l, col_l, b0);
        wtrans_kernel<<<dim3(16, 16, nb), 256, 0, stream>>>(wbuf, wT);
        feat_a_kernel<<<dim3(8, 8, nb), 256, 0, stream>>>(
            wbuf, bT, mask_a, flag, row_l, mean_b, d_out, b0);
        feat_b_kernel<<<dim3(8, 8, nb), 256, 0, stream>>>(
            wT, aT, mask_b, flag, col_l, mean_a, d_out, b0);
    }
}

// Round 2
// 909.906 us; speedup vs baseline: 1.0083x; 1.0083x over previous
//
#include <hip/hip_runtime.h>

#define NB 32
#define L 1024
#define H 1024

typedef __attribute__((ext_vector_type(4))) float floatx4;
typedef __attribute__((ext_vector_type(8))) short shortx8;
typedef __attribute__((ext_vector_type(8))) unsigned short ushortx8;

__device__ __forceinline__ unsigned short f2bf(float f) {
    union { float f; unsigned int u; } v; v.f = f;
    unsigned int u = v.u;
    u += 0x7fffu + ((u >> 16) & 1u);   // round-to-nearest-even
    return (unsigned short)(u >> 16);
}
__device__ __forceinline__ float bf2f(unsigned short h) {
    union { unsigned int u; float f; } v; v.u = ((unsigned int)h) << 16;
    return v.f;
}

// async global->LDS, 16B per lane. Dest must be wave-uniform base + lane*16.
__device__ __forceinline__ void gload_lds16(const void* g, void* l) {
    __builtin_amdgcn_global_load_lds(
        (const __attribute__((address_space(1))) unsigned int*)g,
        (__attribute__((address_space(3))) unsigned int*)l, 16, 0, 0);
}

// T1: XCD batch-chunk swizzle. Grid is flat n = nb*64 blocks (n % 8 == 0).
// Dispatch index round-robins XCDs, so give XCD k the contiguous work chunk
// [k*n/8, (k+1)*n/8) -> each XCD owns nb/8 whole batches (4 MB panels fit L2).
__device__ __forceinline__ void swz_tile(int nb, int& bi_l, int& tx, int& ty) {
    int fid = blockIdx.x;
    int wid = (fid & 7) * (nb * 8) + (fid >> 3);
    bi_l = wid >> 6;
    int t = wid & 63;
    tx = t & 7;
    ty = t >> 3;
}

// ---- dtype detection: bf16 vs fp32 materialization of the float tensors ----
__global__ void detect_kernel(const unsigned short* a, int* flag) {
    int tid = threadIdx.x;
    unsigned short u = a[tid];
    int e = (u >> 7) & 0xff;
    int ok = (u == 0) || (e >= 116 && e <= 136);
    unsigned long long ball = __ballot(ok != 0);
    if (tid == 0) flag[0] = (__popcll(ball) >= 56) ? 1 : 0;
}

__device__ __forceinline__ void store_out(void* out, size_t eidx, float v, int isbf) {
    if (isbf) ((unsigned short*)out)[eidx] = f2bf(v);
    else      ((float*)out)[eidx] = v;
}

// Produce bf16 transposes aT/bT (+ per-(b,h) sum accumulation for means).
// On the fp32 path additionally materialize contiguous bf16 a_c/b_c (the bf16
// path reads the original tensors directly in score_kernel).
// grid: (H/64, L/64, nb*2); block 256.
__global__ __launch_bounds__(256) void convT_kernel(
    const void* A, const void* Bm, const int* flag,
    unsigned short* a_c, unsigned short* b_c,
    unsigned short* aT, unsigned short* bT,
    float* mean_a, float* mean_b, int b0) {
    __shared__ __align__(16) unsigned short T[64][80];
    int z = blockIdx.z;
    int which = z & 1, bi_l = z >> 1, bi = b0 + bi_l;
    int s0 = blockIdx.y * 64, h0 = blockIdx.x * 64;
    const void* src = which ? Bm : A;
    unsigned short* xc = which ? b_c : a_c;
    unsigned short* xT = which ? bT : aT;
    float* msum = which ? mean_b : mean_a;
    int isbf = flag[0];
    int tid = threadIdx.x;

    int r = tid >> 2, c0 = (tid & 3) * 16;
    size_t gin = (size_t)bi * L * H + (size_t)(s0 + r) * H + h0 + c0;
    unsigned short v[16];
    if (isbf) {
        const unsigned short* p = (const unsigned short*)src + gin;
        *(ushortx8*)&v[0] = *(const ushortx8*)p;
        *(ushortx8*)&v[8] = *(const ushortx8*)(p + 8);
    } else {
        const float* p = (const float*)src + gin;
#pragma unroll
        for (int u = 0; u < 16; u += 4) {
            float4 f = *(const float4*)(p + u);
            v[u] = f2bf(f.x); v[u + 1] = f2bf(f.y);
            v[u + 2] = f2bf(f.z); v[u + 3] = f2bf(f.w);
        }
    }
    *(ushortx8*)&T[r][c0] = *(const ushortx8*)&v[0];
    *(ushortx8*)&T[r][c0 + 8] = *(const ushortx8*)&v[8];
    if (!isbf) {   // bf16 path reads originals; only fp32 needs converted copies
        size_t gco = (size_t)bi_l * L * H + (size_t)(s0 + r) * H + h0 + c0;
        *(ushortx8*)&xc[gco] = *(const ushortx8*)&v[0];
        *(ushortx8*)&xc[gco + 8] = *(const ushortx8*)&v[8];
    }
    __syncthreads();

    int hr = tid >> 2, sc0 = (tid & 3) * 16;
    unsigned short tv2[16];
    float ms = 0.f;
#pragma unroll
    for (int u = 0; u < 16; ++u) {
        unsigned short q = T[sc0 + u][hr];
        tv2[u] = q;
        ms += bf2f(q);
    }
    size_t gto = (size_t)bi_l * (size_t)H * L + (size_t)(h0 + hr) * L + s0 + sc0;
    *(ushortx8*)&xT[gto] = *(const ushortx8*)&tv2[0];
    *(ushortx8*)&xT[gto + 8] = *(const ushortx8*)&tv2[8];
    // reduce the 4 lanes sharing hr, then one atomic per (h)
    ms += __shfl_xor(ms, 1);
    ms += __shfl_xor(ms, 2);
    if ((tid & 3) == 0) atomicAdd(&msum[bi * H + h0 + hr], ms);
}

// m97-structure K-loop: C(128x128) += A(128xK) * B(128xK)^T, both operands
// k-contiguous bf16 rows. LDS [128][32] u16 unpadded (global_load_lds needs
// linear dest). 2 barriers / K-step.
__device__ __forceinline__ void gemm_kk(
    const unsigned short* Arow, const unsigned short* Brow,
    int lda, int ldb, int K,
    unsigned short* AsBase, unsigned short* BsBase,
    int tid, floatx4 (&acc)[4][4]) {
    int lane = tid & 63;
    int wid = tid >> 6;
    int wm = wid >> 1, wn = wid & 1;
    int lane15 = lane & 15, quad = lane >> 4;

    for (int k0 = 0; k0 < K; k0 += 32) {
#pragma unroll
        for (int it = 0; it < 4; ++it) {
            int idx = (it & 1) * 256 + tid;       // 0..511
            int rr = idx >> 2, cc = (idx & 3) * 8;
            const unsigned short* src = (it < 2)
                ? (Arow + (size_t)rr * lda + k0 + cc)
                : (Brow + (size_t)rr * ldb + k0 + cc);
            unsigned short* dst = ((it < 2) ? AsBase : BsBase) + idx * 8;
            gload_lds16(src, dst);
        }
        __syncthreads();
        shortx8 af[4], bfr[4];
#pragma unroll
        for (int i = 0; i < 4; ++i)
            af[i] = *(const shortx8*)(AsBase + (wm * 64 + i * 16 + lane15) * 32 + quad * 8);
#pragma unroll
        for (int j = 0; j < 4; ++j)
            bfr[j] = *(const shortx8*)(BsBase + (wn * 64 + j * 16 + lane15) * 32 + quad * 8);
#pragma unroll
        for (int i = 0; i < 4; ++i)
#pragma unroll
            for (int j = 0; j < 4; ++j)
                acc[i][j] = __builtin_amdgcn_mfma_f32_16x16x32_bf16(af[i], bfr[j], acc[i][j], 0, 0, 0);
        __syncthreads();
    }
}

// S = a.b^T * tau; w = mask ? exp(S) : 0 (bf16). Fused row/col sums
// (shuffle-reduce + atomics) AND fused wT write (LDS-bounce transpose).
__global__ __launch_bounds__(256) void score_kernel(
    const void* Araw, const void* Braw,
    const unsigned short* a_c, const unsigned short* b_c,
    const int* mask_a, const int* mask_b, const void* temp, const int* flag,
    unsigned short* w, unsigned short* wT,
    float* row_l, float* col_l, int b0, int nb) {
    __shared__ __align__(16) unsigned short lds_all[8192];  // 16 KiB
    unsigned short* As = lds_all;
    unsigned short* Bs = lds_all + 4096;
    int bi_l, tx, ty;
    swz_tile(nb, bi_l, tx, ty);
    int bi = b0 + bi_l;
    int s0 = ty * 128, t0 = tx * 128;
    int tid = threadIdx.x;
    int isbf = flag[0];

    floatx4 acc[4][4];
#pragma unroll
    for (int i = 0; i < 4; ++i)
#pragma unroll
        for (int j = 0; j < 4; ++j)
#pragma unroll
            for (int rr = 0; rr < 4; ++rr) acc[i][j][rr] = 0.f;

    const unsigned short* Arow = isbf
        ? (const unsigned short*)Araw + (size_t)bi * L * H + (size_t)s0 * H
        : a_c + (size_t)bi_l * L * H + (size_t)s0 * H;
    const unsigned short* Brow = isbf
        ? (const unsigned short*)Braw + (size_t)bi * L * H + (size_t)t0 * H
        : b_c + (size_t)bi_l * L * H + (size_t)t0 * H;
    gemm_kk(Arow, Brow, H, H, H, As, Bs, tid, acc);

    float tv = isbf ? bf2f(((const unsigned short*)temp)[0]) : ((const float*)temp)[0];
    int lane = tid & 63, wid = tid >> 6;
    int wm = wid >> 1, wn = wid & 1;
    int lane15 = lane & 15, quad = lane >> 4;

    int mb[4];
#pragma unroll
    for (int j = 0; j < 4; ++j)
        mb[j] = mask_b[bi * L + t0 + wn * 64 + j * 16 + lane15];
    size_t wbase = (size_t)bi_l * L * L;
    float colp[4] = {0.f, 0.f, 0.f, 0.f};
#pragma unroll
    for (int i = 0; i < 4; ++i) {
#pragma unroll
        for (int r = 0; r < 4; ++r) {
            int s = s0 + wm * 64 + i * 16 + quad * 4 + r;
            int ma = mask_a[bi * L + s];
            float rp = 0.f;
#pragma unroll
            for (int j = 0; j < 4; ++j) {
                int t = t0 + wn * 64 + j * 16 + lane15;
                float wv = (ma && mb[j]) ? __expf(acc[i][j][r] * tv) : 0.f;
                unsigned short wq = f2bf(wv);
                w[wbase + (size_t)s * L + t] = wq;
                float wf = bf2f(wq);       // sum exactly what we stored
                rp += wf;
                colp[j] += wf;
            }
            rp += __shfl_xor(rp, 1);
            rp += __shfl_xor(rp, 2);
            rp += __shfl_xor(rp, 4);
            rp += __shfl_xor(rp, 8);
            if (lane15 == 0) atomicAdd(&row_l[bi * L + s], rp);
        }
    }
#pragma unroll
    for (int j = 0; j < 4; ++j) {
        float cp = colp[j];
        cp += __shfl_xor(cp, 16);
        cp += __shfl_xor(cp, 32);
        if (quad == 0) {
            int t = t0 + wn * 64 + j * 16 + lane15;
            atomicAdd(&col_l[bi * L + t], cp);
        }
    }

    // Fused wT: transpose the tile through LDS, 32 t-columns per pass.
    // Recompute exp from the live acc (cheaper than +32 VGPR of retained wq).
    // Slab stride 34 u16 (=68 B): transposed reads walk banks bijectively.
    unsigned short* slab = lds_all;   // 128*34 u16 = 8704 B, fits the 16 KiB
    int c = wn * 16 + lane15;
    for (int j = 0; j < 4; ++j) {
        __syncthreads();
#pragma unroll
        for (int i = 0; i < 4; ++i) {
#pragma unroll
            for (int r = 0; r < 4; ++r) {
                int sl = wm * 64 + i * 16 + quad * 4 + r;
                int ma = mask_a[bi * L + s0 + sl];
                float wv = (ma && mb[j]) ? __expf(acc[i][j][r] * tv) : 0.f;
                slab[sl * 34 + c] = f2bf(wv);
            }
        }
        __syncthreads();
        int cc = tid >> 3, sch = (tid & 7) * 16;
        __align__(16) unsigned short o[16];
#pragma unroll
        for (int u = 0; u < 16; ++u) o[u] = slab[(sch + u) * 34 + cc];
        int t = t0 + (cc >> 4) * 64 + j * 16 + (cc & 15);
        size_t go = (size_t)bi_l * L * L + (size_t)t * L + s0 + sch;
        *(ushortx8*)&wT[go] = *(const ushortx8*)&o[0];
        *(ushortx8*)&wT[go + 8] = *(const ushortx8*)&o[8];
    }
}

// feature_a[s,h] = ma ? (sum_t w[s,t] b[t,h]) / row_l[s] : mean_b[h]
__global__ __launch_bounds__(256) void feat_a_kernel(
    const unsigned short* w, const unsigned short* bT, const int* mask_a,
    const int* flag, const float* row_l, const float* mean_b, void* out,
    int b0, int nb) {
    __shared__ __align__(16) unsigned short As[128 * 32];
    __shared__ __align__(16) unsigned short Bs[128 * 32];
    int bi_l, tx, ty;
    swz_tile(nb, bi_l, tx, ty);
    int bi = b0 + bi_l;
    int s0 = ty * 128, h0 = tx * 128;
    int tid = threadIdx.x;

    floatx4 acc[4][4];
#pragma unroll
    for (int i = 0; i < 4; ++i)
#pragma unroll
        for (int j = 0; j < 4; ++j)
#pragma unroll
            for (int rr = 0; rr < 4; ++rr) acc[i][j][rr] = 0.f;

    gemm_kk(w + (size_t)bi_l * L * L + (size_t)s0 * L,
            bT + (size_t)bi_l * (size_t)H * L + (size_t)h0 * L,
            L, L, L, As, Bs, tid, acc);

    int isbf = flag[0];
    int lane = tid & 63, wid = tid >> 6;
    int wm = wid >> 1, wn = wid & 1;
    int lane15 = lane & 15, quad = lane >> 4;
    const float invL = 1.f / (float)L;
#pragma unroll
    for (int i = 0; i < 4; ++i) {
#pragma unroll
        for (int r = 0; r < 4; ++r) {
            int s = s0 + wm * 64 + i * 16 + quad * 4 + r;
            int ma = mask_a[bi * L + s];
            float scale = ma ? (1.f / row_l[bi * L + s]) : 0.f;
#pragma unroll
            for (int j = 0; j < 4; ++j) {
                int h = h0 + wn * 64 + j * 16 + lane15;
                float v = ma ? acc[i][j][r] * scale : mean_b[bi * H + h] * invL;
                store_out(out, (size_t)bi * L * H + (size_t)s * H + h, v, isbf);
            }
        }
    }
}

// feature_b[t,h] = mb ? (sum_s w[s,t] a[s,h]) / col_l[t] : mean_a[h]
__global__ __launch_bounds__(256) void feat_b_kernel(
    const unsigned short* wT, const unsigned short* aT, const int* mask_b,
    const int* flag, const float* col_l, const float* mean_a, void* out,
    int b0, int nb) {
    __shared__ __align__(16) unsigned short As[128 * 32];
    __shared__ __align__(16) unsigned short Bs[128 * 32];
    int bi_l, tx, ty;
    swz_tile(nb, bi_l, tx, ty);
    int bi = b0 + bi_l;
    int t0 = ty * 128, h0 = tx * 128;
    int tid = threadIdx.x;

    floatx4 acc[4][4];
#pragma unroll
    for (int i = 0; i < 4; ++i)
#pragma unroll
        for (int j = 0; j < 4; ++j)
#pragma unroll
            for (int rr = 0; rr < 4; ++rr) acc[i][j][rr] = 0.f;

    gemm_kk(wT + (size_t)bi_l * L * L + (size_t)t0 * L,
            aT + (size_t)bi_l * (size_t)H * L + (size_t)h0 * L,
            L, L, L, As, Bs, tid, acc);

    int isbf = flag[0];
    int lane = tid & 63, wid = tid >> 6;
    int wm = wid >> 1, wn = wid & 1;
    int lane15 = lane & 15, quad = lane >> 4;
    const float invL = 1.f / (float)L;
    const size_t FEAT_B_OFF = (size_t)NB * L * H;
#pragma unroll
    for (int i = 0; i < 4; ++i) {
#pragma unroll
        for (int r = 0; r < 4; ++r) {
            int t = t0 + wm * 64 + i * 16 + quad * 4 + r;
            int mbv = mask_b[bi * L + t];
            float scale = mbv ? (1.f / col_l[bi * L + t]) : 0.f;
#pragma unroll
            for (int j = 0; j < 4; ++j) {
                int h = h0 + wn * 64 + j * 16 + lane15;
                float v = mbv ? acc[i][j][r] * scale : mean_a[bi * H + h] * invL;
                store_out(out, FEAT_B_OFF + (size_t)bi * L * H + (size_t)t * H + h, v, isbf);
            }
        }
    }
}

extern "C" void kernel_launch(void* const* d_in, const int* in_sizes, int n_in,
                              void* d_out, int out_size, void* d_ws, size_t ws_size,
                              hipStream_t stream) {
    const void* a = d_in[0];
    const void* b = d_in[1];
    const int* mask_a = (const int*)d_in[2];
    const int* mask_b = (const int*)d_in[3];
    const void* temp = d_in[4];

    // Workspace: stats first (zeroed), then 6 chunk-sized bf16 buffers.
    char* wsp = (char*)d_ws;
    float* row_l  = (float*)wsp;                       // NB*L
    float* col_l  = row_l + (size_t)NB * L;            // NB*L
    float* mean_a = col_l + (size_t)NB * L;            // NB*H (raw sums)
    float* mean_b = mean_a + (size_t)NB * H;           // NB*H (raw sums)
    int*   flag   = (int*)(mean_b + (size_t)NB * H);
    const size_t stats_bytes = ((size_t)NB * L * 2 + (size_t)NB * H * 2) * 4 + 256;

    const size_t per_batch = 6 * (size_t)L * H * 2;    // a_c,b_c,aT,bT,w,wT = 12 MiB
    size_t wavail = (ws_size > stats_bytes) ? ws_size - stats_bytes : 0;
    int chunk = (int)(wavail / per_batch);
    if (chunk < 1) chunk = 1;
    if (chunk > NB) chunk = NB;

    unsigned short* a_c  = (unsigned short*)(wsp + stats_bytes);
    unsigned short* b_c  = a_c + (size_t)chunk * L * H;
    unsigned short* aT   = b_c + (size_t)chunk * L * H;
    unsigned short* bT   = aT  + (size_t)chunk * L * H;
    unsigned short* wbuf = bT  + (size_t)chunk * L * H;
    unsigned short* wT   = wbuf + (size_t)chunk * L * L;

    hipMemsetAsync(d_ws, 0, stats_bytes, stream);      // zero row/col/mean accums
    detect_kernel<<<1, 64, 0, stream>>>((const unsigned short*)a, flag);

    for (int b0 = 0; b0 < NB; b0 += chunk) {
        int nb = (NB - b0 < chunk) ? (NB - b0) : chunk;
        convT_kernel<<<dim3(16, 16, nb * 2), 256, 0, stream>>>(
            a, b, flag, a_c, b_c, aT, bT, mean_a, mean_b, b0);
        score_kernel<<<dim3(nb * 64), 256, 0, stream>>>(
            a, b, a_c, b_c, mask_a, mask_b, temp, flag, wbuf, wT,
            row_l, col_l, b0, nb);
        feat_a_kernel<<<dim3(nb * 64), 256, 0, stream>>>(
            wbuf, bT, mask_a, flag, row_l, mean_b, d_out, b0, nb);
        feat_b_kernel<<<dim3(nb * 64), 256, 0, stream>>>(
            wT, aT, mask_b, flag, col_l, mean_a, d_out, b0, nb);
    }
}

// Round 3
// 889.409 us; speedup vs baseline: 1.0315x; 1.0230x over previous
//
#include <hip/hip_runtime.h>

#define NB 32
#define L 1024
#define H 1024

typedef __attribute__((ext_vector_type(4))) float floatx4;
typedef __attribute__((ext_vector_type(8))) short shortx8;
typedef __attribute__((ext_vector_type(8))) unsigned short ushortx8;

__device__ __forceinline__ unsigned short f2bf(float f) {
    union { float f; unsigned int u; } v; v.f = f;
    unsigned int u = v.u;
    u += 0x7fffu + ((u >> 16) & 1u);   // round-to-nearest-even
    return (unsigned short)(u >> 16);
}
__device__ __forceinline__ float bf2f(unsigned short h) {
    union { unsigned int u; float f; } v; v.u = ((unsigned int)h) << 16;
    return v.f;
}

// async global->LDS, 16B per lane. Dest must be wave-uniform base + lane*16.
__device__ __forceinline__ void gload_lds16(const void* g, void* l) {
    __builtin_amdgcn_global_load_lds(
        (const __attribute__((address_space(1))) unsigned int*)g,
        (__attribute__((address_space(3))) unsigned int*)l, 16, 0, 0);
}

// T1: XCD batch-chunk swizzle. Grid is flat n = nb*64 blocks (n % 8 == 0).
__device__ __forceinline__ void swz_tile(int nb, int& bi_l, int& tx, int& ty) {
    int fid = blockIdx.x;
    int wid = (fid & 7) * (nb * 8) + (fid >> 3);
    bi_l = wid >> 6;
    int t = wid & 63;
    tx = t & 7;
    ty = t >> 3;
}

// ---- dtype detection: bf16 vs fp32 materialization of the float tensors ----
__global__ void detect_kernel(const unsigned short* a, int* flag) {
    int tid = threadIdx.x;
    unsigned short u = a[tid];
    int e = (u >> 7) & 0xff;
    int ok = (u == 0) || (e >= 116 && e <= 136);
    unsigned long long ball = __ballot(ok != 0);
    if (tid == 0) flag[0] = (__popcll(ball) >= 56) ? 1 : 0;
}

__device__ __forceinline__ void store_out(void* out, size_t eidx, float v, int isbf) {
    if (isbf) ((unsigned short*)out)[eidx] = f2bf(v);
    else      ((float*)out)[eidx] = v;
}

// Produce bf16 transposes aT/bT (+ per-(b,h) sums for means). fp32 path also
// materializes contiguous bf16 a_c/b_c. grid: (H/64, L/64, nb*2); block 256.
__global__ __launch_bounds__(256) void convT_kernel(
    const void* A, const void* Bm, const int* flag,
    unsigned short* a_c, unsigned short* b_c,
    unsigned short* aT, unsigned short* bT,
    float* mean_a, float* mean_b, int b0) {
    __shared__ __align__(16) unsigned short T[64][80];
    int z = blockIdx.z;
    int which = z & 1, bi_l = z >> 1, bi = b0 + bi_l;
    int s0 = blockIdx.y * 64, h0 = blockIdx.x * 64;
    const void* src = which ? Bm : A;
    unsigned short* xc = which ? b_c : a_c;
    unsigned short* xT = which ? bT : aT;
    float* msum = which ? mean_b : mean_a;
    int isbf = flag[0];
    int tid = threadIdx.x;

    int r = tid >> 2, c0 = (tid & 3) * 16;
    size_t gin = (size_t)bi * L * H + (size_t)(s0 + r) * H + h0 + c0;
    unsigned short v[16];
    if (isbf) {
        const unsigned short* p = (const unsigned short*)src + gin;
        *(ushortx8*)&v[0] = *(const ushortx8*)p;
        *(ushortx8*)&v[8] = *(const ushortx8*)(p + 8);
    } else {
        const float* p = (const float*)src + gin;
#pragma unroll
        for (int u = 0; u < 16; u += 4) {
            float4 f = *(const float4*)(p + u);
            v[u] = f2bf(f.x); v[u + 1] = f2bf(f.y);
            v[u + 2] = f2bf(f.z); v[u + 3] = f2bf(f.w);
        }
    }
    *(ushortx8*)&T[r][c0] = *(const ushortx8*)&v[0];
    *(ushortx8*)&T[r][c0 + 8] = *(const ushortx8*)&v[8];
    if (!isbf) {
        size_t gco = (size_t)bi_l * L * H + (size_t)(s0 + r) * H + h0 + c0;
        *(ushortx8*)&xc[gco] = *(const ushortx8*)&v[0];
        *(ushortx8*)&xc[gco + 8] = *(const ushortx8*)&v[8];
    }
    __syncthreads();

    int hr = tid >> 2, sc0 = (tid & 3) * 16;
    unsigned short tv2[16];
    float ms = 0.f;
#pragma unroll
    for (int u = 0; u < 16; ++u) {
        unsigned short q = T[sc0 + u][hr];
        tv2[u] = q;
        ms += bf2f(q);
    }
    size_t gto = (size_t)bi_l * (size_t)H * L + (size_t)(h0 + hr) * L + s0 + sc0;
    *(ushortx8*)&xT[gto] = *(const ushortx8*)&tv2[0];
    *(ushortx8*)&xT[gto + 8] = *(const ushortx8*)&tv2[8];
    ms += __shfl_xor(ms, 1);
    ms += __shfl_xor(ms, 2);
    if ((tid & 3) == 0) atomicAdd(&msum[bi * H + h0 + hr], ms);
}

// 64x64 bf16 tile transpose: wT[t][s] = w[s][t]. grid (16,16,nb); block 256.
__global__ __launch_bounds__(256) void wtrans_kernel(const unsigned short* w,
                                                     unsigned short* wT) {
    __shared__ __align__(16) unsigned short T[64][80];
    int bi_l = blockIdx.z;
    int s0 = blockIdx.y * 64, t0 = blockIdx.x * 64;
    int tid = threadIdx.x;
    int r = tid >> 2, c0 = (tid & 3) * 16;
    size_t gin = (size_t)bi_l * L * L + (size_t)(s0 + r) * L + t0 + c0;
    *(ushortx8*)&T[r][c0] = *(const ushortx8*)&w[gin];
    *(ushortx8*)&T[r][c0 + 8] = *(const ushortx8*)&w[gin + 8];
    __syncthreads();
    int tr = tid >> 2, sc0 = (tid & 3) * 16;
    unsigned short o[16];
#pragma unroll
    for (int u = 0; u < 16; ++u) o[u] = T[sc0 + u][tr];
    size_t gout = (size_t)bi_l * L * L + (size_t)(t0 + tr) * L + s0 + sc0;
    *(ushortx8*)&wT[gout] = *(const ushortx8*)&o[0];
    *(ushortx8*)&wT[gout + 8] = *(const ushortx8*)&o[8];
}

// Stage one 128x32 A-tile + 128x32 B-tile into LDS (16 gloads per wave-group).
__device__ __forceinline__ void stage_tiles(
    const unsigned short* Arow, const unsigned short* Brow,
    int lda, int ldb, int k0,
    unsigned short* As, unsigned short* Bs, int tid) {
#pragma unroll
    for (int it = 0; it < 4; ++it) {
        int idx = (it & 1) * 256 + tid;       // 0..511
        int rr = idx >> 2, cc = (idx & 3) * 8;
        const unsigned short* src = (it < 2)
            ? (Arow + (size_t)rr * lda + k0 + cc)
            : (Brow + (size_t)rr * ldb + k0 + cc);
        unsigned short* dst = ((it < 2) ? As : Bs) + idx * 8;
        gload_lds16(src, dst);
    }
}

// Counted-vmcnt depth-2 double-buffered K-loop (T3/T4-lite + T5).
// C(128x128) += A(128xK) * B(128xK)^T, both operands k-contiguous bf16.
// Raw s_barrier (NOT __syncthreads: that drains vmcnt(0) -> the m97 stall).
// Invariant: stage t+1 stays in flight across tile t's compute (vmcnt(4)).
// Buf-overwrite race handled by lgkmcnt(0)+sched_barrier before 2nd barrier.
__device__ __forceinline__ void gemm_kk_pipe(
    const unsigned short* Arow, const unsigned short* Brow,
    int lda, int ldb, int K,
    unsigned short* lds,    // 4 x 4096 u16: As0,Bs0,As1,Bs1
    int tid, floatx4 (&acc)[4][4]) {
    int lane = tid & 63, wid = tid >> 6;
    int wm = wid >> 1, wn = wid & 1;
    int lane15 = lane & 15, quad = lane >> 4;
    unsigned short* As0 = lds;
    unsigned short* Bs0 = lds + 4096;
    unsigned short* As1 = lds + 8192;
    unsigned short* Bs1 = lds + 12288;
    int NT = K >> 5;

    stage_tiles(Arow, Brow, lda, ldb, 0, As0, Bs0, tid);
    stage_tiles(Arow, Brow, lda, ldb, 32, As1, Bs1, tid);

    for (int t = 0; t < NT; ++t) {
        unsigned short* As = (t & 1) ? As1 : As0;
        unsigned short* Bs = (t & 1) ? Bs1 : Bs0;
        // wait for stage t (stage t+1 keeps flying, except at the tail)
        if (t < NT - 1) asm volatile("s_waitcnt vmcnt(4)" ::: "memory");
        else            asm volatile("s_waitcnt vmcnt(0)" ::: "memory");
        __builtin_amdgcn_s_barrier();           // all waves' stage-t writes done
        asm volatile("" ::: "memory");          // no load hoists above barrier
        shortx8 af[4], bfr[4];
#pragma unroll
        for (int i = 0; i < 4; ++i)
            af[i] = *(const shortx8*)(As + (wm * 64 + i * 16 + lane15) * 32 + quad * 8);
#pragma unroll
        for (int j = 0; j < 4; ++j)
            bfr[j] = *(const shortx8*)(Bs + (wn * 64 + j * 16 + lane15) * 32 + quad * 8);
        asm volatile("s_waitcnt lgkmcnt(0)" ::: "memory");  // my reads complete
        __builtin_amdgcn_sched_barrier(0);
        __builtin_amdgcn_s_barrier();           // everyone's reads complete
        asm volatile("" ::: "memory");          // no stage hoists above barrier
        if (t + 2 < NT)                          // overwrite buf p, loads fly
            stage_tiles(Arow, Brow, lda, ldb, (t + 2) * 32, As, Bs, tid);
        __builtin_amdgcn_s_setprio(1);
#pragma unroll
        for (int i = 0; i < 4; ++i)
#pragma unroll
            for (int j = 0; j < 4; ++j)
                acc[i][j] = __builtin_amdgcn_mfma_f32_16x16x32_bf16(af[i], bfr[j], acc[i][j], 0, 0, 0);
        __builtin_amdgcn_s_setprio(0);
    }
    __builtin_amdgcn_s_barrier();
}

// S = a.b^T * tau; w = mask ? exp(S) : 0 (bf16). Fused row/col sums.
__global__ __launch_bounds__(256) void score_kernel(
    const void* Araw, const void* Braw,
    const unsigned short* a_c, const unsigned short* b_c,
    const int* mask_a, const int* mask_b, const void* temp, const int* flag,
    unsigned short* w, float* row_l, float* col_l, int b0, int nb) {
    __shared__ __align__(16) unsigned short lds[16384];   // 32 KiB: 2x dbuf
    int bi_l, tx, ty;
    swz_tile(nb, bi_l, tx, ty);
    int bi = b0 + bi_l;
    int s0 = ty * 128, t0 = tx * 128;
    int tid = threadIdx.x;
    int isbf = flag[0];

    floatx4 acc[4][4];
#pragma unroll
    for (int i = 0; i < 4; ++i)
#pragma unroll
        for (int j = 0; j < 4; ++j)
#pragma unroll
            for (int rr = 0; rr < 4; ++rr) acc[i][j][rr] = 0.f;

    const unsigned short* Arow = isbf
        ? (const unsigned short*)Araw + (size_t)bi * L * H + (size_t)s0 * H
        : a_c + (size_t)bi_l * L * H + (size_t)s0 * H;
    const unsigned short* Brow = isbf
        ? (const unsigned short*)Braw + (size_t)bi * L * H + (size_t)t0 * H
        : b_c + (size_t)bi_l * L * H + (size_t)t0 * H;
    gemm_kk_pipe(Arow, Brow, H, H, H, lds, tid, acc);

    float tv = isbf ? bf2f(((const unsigned short*)temp)[0]) : ((const float*)temp)[0];
    int lane = tid & 63, wid = tid >> 6;
    int wm = wid >> 1, wn = wid & 1;
    int lane15 = lane & 15, quad = lane >> 4;

    int mb[4];
#pragma unroll
    for (int j = 0; j < 4; ++j)
        mb[j] = mask_b[bi * L + t0 + wn * 64 + j * 16 + lane15];
    size_t wbase = (size_t)bi_l * L * L;
    float colp[4] = {0.f, 0.f, 0.f, 0.f};
#pragma unroll
    for (int i = 0; i < 4; ++i) {
#pragma unroll
        for (int r = 0; r < 4; ++r) {
            int s = s0 + wm * 64 + i * 16 + quad * 4 + r;
            int ma = mask_a[bi * L + s];
            float rp = 0.f;
#pragma unroll
            for (int j = 0; j < 4; ++j) {
                int t = t0 + wn * 64 + j * 16 + lane15;
                float wv = (ma && mb[j]) ? __expf(acc[i][j][r] * tv) : 0.f;
                unsigned short wq = f2bf(wv);
                w[wbase + (size_t)s * L + t] = wq;
                float wf = bf2f(wq);       // sum exactly what we stored
                rp += wf;
                colp[j] += wf;
            }
            rp += __shfl_xor(rp, 1);
            rp += __shfl_xor(rp, 2);
            rp += __shfl_xor(rp, 4);
            rp += __shfl_xor(rp, 8);
            if (lane15 == 0) atomicAdd(&row_l[bi * L + s], rp);
        }
    }
#pragma unroll
    for (int j = 0; j < 4; ++j) {
        float cp = colp[j];
        cp += __shfl_xor(cp, 16);
        cp += __shfl_xor(cp, 32);
        if (quad == 0) {
            int t = t0 + wn * 64 + j * 16 + lane15;
            atomicAdd(&col_l[bi * L + t], cp);
        }
    }
}

// feature_a[s,h] = ma ? (sum_t w[s,t] b[t,h]) / row_l[s] : mean_b[h]
__global__ __launch_bounds__(256) void feat_a_kernel(
    const unsigned short* w, const unsigned short* bT, const int* mask_a,
    const int* flag, const float* row_l, const float* mean_b, void* out,
    int b0, int nb) {
    __shared__ __align__(16) unsigned short lds[16384];
    int bi_l, tx, ty;
    swz_tile(nb, bi_l, tx, ty);
    int bi = b0 + bi_l;
    int s0 = ty * 128, h0 = tx * 128;
    int tid = threadIdx.x;

    floatx4 acc[4][4];
#pragma unroll
    for (int i = 0; i < 4; ++i)
#pragma unroll
        for (int j = 0; j < 4; ++j)
#pragma unroll
            for (int rr = 0; rr < 4; ++rr) acc[i][j][rr] = 0.f;

    gemm_kk_pipe(w + (size_t)bi_l * L * L + (size_t)s0 * L,
                 bT + (size_t)bi_l * (size_t)H * L + (size_t)h0 * L,
                 L, L, L, lds, tid, acc);

    int isbf = flag[0];
    int lane = tid & 63, wid = tid >> 6;
    int wm = wid >> 1, wn = wid & 1;
    int lane15 = lane & 15, quad = lane >> 4;
    const float invL = 1.f / (float)L;
#pragma unroll
    for (int i = 0; i < 4; ++i) {
#pragma unroll
        for (int r = 0; r < 4; ++r) {
            int s = s0 + wm * 64 + i * 16 + quad * 4 + r;
            int ma = mask_a[bi * L + s];
            float scale = ma ? (1.f / row_l[bi * L + s]) : 0.f;
#pragma unroll
            for (int j = 0; j < 4; ++j) {
                int h = h0 + wn * 64 + j * 16 + lane15;
                float v = ma ? acc[i][j][r] * scale : mean_b[bi * H + h] * invL;
                store_out(out, (size_t)bi * L * H + (size_t)s * H + h, v, isbf);
            }
        }
    }
}

// feature_b[t,h] = mb ? (sum_s w[s,t] a[s,h]) / col_l[t] : mean_a[h]
__global__ __launch_bounds__(256) void feat_b_kernel(
    const unsigned short* wT, const unsigned short* aT, const int* mask_b,
    const int* flag, const float* col_l, const float* mean_a, void* out,
    int b0, int nb) {
    __shared__ __align__(16) unsigned short lds[16384];
    int bi_l, tx, ty;
    swz_tile(nb, bi_l, tx, ty);
    int bi = b0 + bi_l;
    int t0 = ty * 128, h0 = tx * 128;
    int tid = threadIdx.x;

    floatx4 acc[4][4];
#pragma unroll
    for (int i = 0; i < 4; ++i)
#pragma unroll
        for (int j = 0; j < 4; ++j)
#pragma unroll
            for (int rr = 0; rr < 4; ++rr) acc[i][j][rr] = 0.f;

    gemm_kk_pipe(wT + (size_t)bi_l * L * L + (size_t)t0 * L,
                 aT + (size_t)bi_l * (size_t)H * L + (size_t)h0 * L,
                 L, L, L, lds, tid, acc);

    int isbf = flag[0];
    int lane = tid & 63, wid = tid >> 6;
    int wm = wid >> 1, wn = wid & 1;
    int lane15 = lane & 15, quad = lane >> 4;
    const float invL = 1.f / (float)L;
    const size_t FEAT_B_OFF = (size_t)NB * L * H;
#pragma unroll
    for (int i = 0; i < 4; ++i) {
#pragma unroll
        for (int r = 0; r < 4; ++r) {
            int t = t0 + wm * 64 + i * 16 + quad * 4 + r;
            int mbv = mask_b[bi * L + t];
            float scale = mbv ? (1.f / col_l[bi * L + t]) : 0.f;
#pragma unroll
            for (int j = 0; j < 4; ++j) {
                int h = h0 + wn * 64 + j * 16 + lane15;
                float v = mbv ? acc[i][j][r] * scale : mean_a[bi * H + h] * invL;
                store_out(out, FEAT_B_OFF + (size_t)bi * L * H + (size_t)t * H + h, v, isbf);
            }
        }
    }
}

extern "C" void kernel_launch(void* const* d_in, const int* in_sizes, int n_in,
                              void* d_out, int out_size, void* d_ws, size_t ws_size,
                              hipStream_t stream) {
    const void* a = d_in[0];
    const void* b = d_in[1];
    const int* mask_a = (const int*)d_in[2];
    const int* mask_b = (const int*)d_in[3];
    const void* temp = d_in[4];

    char* wsp = (char*)d_ws;
    float* row_l  = (float*)wsp;                       // NB*L
    float* col_l  = row_l + (size_t)NB * L;            // NB*L
    float* mean_a = col_l + (size_t)NB * L;            // NB*H (raw sums)
    float* mean_b = mean_a + (size_t)NB * H;           // NB*H (raw sums)
    int*   flag   = (int*)(mean_b + (size_t)NB * H);
    const size_t stats_bytes = ((size_t)NB * L * 2 + (size_t)NB * H * 2) * 4 + 256;

    const size_t per_batch = 6 * (size_t)L * H * 2;    // a_c,b_c,aT,bT,w,wT
    size_t wavail = (ws_size > stats_bytes) ? ws_size - stats_bytes : 0;
    int chunk = (int)(wavail / per_batch);
    if (chunk < 1) chunk = 1;
    if (chunk > NB) chunk = NB;

    unsigned short* a_c  = (unsigned short*)(wsp + stats_bytes);
    unsigned short* b_c  = a_c + (size_t)chunk * L * H;
    unsigned short* aT   = b_c + (size_t)chunk * L * H;
    unsigned short* bT   = aT  + (size_t)chunk * L * H;
    unsigned short* wbuf = bT  + (size_t)chunk * L * H;
    unsigned short* wT   = wbuf + (size_t)chunk * L * L;

    hipMemsetAsync(d_ws, 0, stats_bytes, stream);      // zero row/col/mean accums
    detect_kernel<<<1, 64, 0, stream>>>((const unsigned short*)a, flag);

    for (int b0 = 0; b0 < NB; b0 += chunk) {
        int nb = (NB - b0 < chunk) ? (NB - b0) : chunk;
        convT_kernel<<<dim3(16, 16, nb * 2), 256, 0, stream>>>(
            a, b, flag, a_c, b_c, aT, bT, mean_a, mean_b, b0);
        score_kernel<<<dim3(nb * 64), 256, 0, stream>>>(
            a, b, a_c, b_c, mask_a, mask_b, temp, flag, wbuf,
            row_l, col_l, b0, nb);
        wtrans_kernel<<<dim3(16, 16, nb), 256, 0, stream>>>(wbuf, wT);
        feat_a_kernel<<<dim3(nb * 64), 256, 0, stream>>>(
            wbuf, bT, mask_a, flag, row_l, mean_b, d_out, b0, nb);
        feat_b_kernel<<<dim3(nb * 64), 256, 0, stream>>>(
            wT, aT, mask_b, flag, col_l, mean_a, d_out, b0, nb);
    }
}

// Round 5
// 872.097 us; speedup vs baseline: 1.0520x; 1.0199x over previous
//
#include <hip/hip_runtime.h>

#define NB 32
#define L 1024
#define H 1024

typedef __attribute__((ext_vector_type(4))) float floatx4;
typedef __attribute__((ext_vector_type(8))) short shortx8;
typedef __attribute__((ext_vector_type(8))) unsigned short ushortx8;

__device__ __forceinline__ unsigned short f2bf(float f) {
    union { float f; unsigned int u; } v; v.f = f;
    unsigned int u = v.u;
    u += 0x7fffu + ((u >> 16) & 1u);   // round-to-nearest-even
    return (unsigned short)(u >> 16);
}
__device__ __forceinline__ float bf2f(unsigned short h) {
    union { unsigned int u; float f; } v; v.u = ((unsigned int)h) << 16;
    return v.f;
}

// async global->LDS, 16B per lane. Dest must be wave-uniform base + lane*16.
__device__ __forceinline__ void gload_lds16(const void* g, void* l) {
    __builtin_amdgcn_global_load_lds(
        (const __attribute__((address_space(1))) unsigned int*)g,
        (__attribute__((address_space(3))) unsigned int*)l, 16, 0, 0);
}

// T1: XCD batch-chunk swizzle. Grid is flat n = nb*64 blocks (n % 8 == 0).
__device__ __forceinline__ void swz_tile(int nb, int& bi_l, int& tx, int& ty) {
    int fid = blockIdx.x;
    int wid = (fid & 7) * (nb * 8) + (fid >> 3);
    bi_l = wid >> 6;
    int t = wid & 63;
    tx = t & 7;
    ty = t >> 3;
}

// ---- dtype detection: bf16 vs fp32 materialization of the float tensors ----
__global__ void detect_kernel(const unsigned short* a, int* flag) {
    int tid = threadIdx.x;
    unsigned short u = a[tid];
    int e = (u >> 7) & 0xff;
    int ok = (u == 0) || (e >= 116 && e <= 136);
    unsigned long long ball = __ballot(ok != 0);
    if (tid == 0) flag[0] = (__popcll(ball) >= 56) ? 1 : 0;
}

__device__ __forceinline__ void store_out(void* out, size_t eidx, float v, int isbf) {
    if (isbf) ((unsigned short*)out)[eidx] = f2bf(v);
    else      ((float*)out)[eidx] = v;
}

// Produce bf16 transposes aT/bT (+ per-(b,h) sums for means). fp32 path also
// materializes contiguous bf16 a_c/b_c. grid: (H/64, L/64, nb*2); block 256.
__global__ __launch_bounds__(256) void convT_kernel(
    const void* A, const void* Bm, const int* flag,
    unsigned short* a_c, unsigned short* b_c,
    unsigned short* aT, unsigned short* bT,
    float* mean_a, float* mean_b, int b0) {
    __shared__ __align__(16) unsigned short T[64][80];
    int z = blockIdx.z;
    int which = z & 1, bi_l = z >> 1, bi = b0 + bi_l;
    int s0 = blockIdx.y * 64, h0 = blockIdx.x * 64;
    const void* src = which ? Bm : A;
    unsigned short* xc = which ? b_c : a_c;
    unsigned short* xT = which ? bT : aT;
    float* msum = which ? mean_b : mean_a;
    int isbf = flag[0];
    int tid = threadIdx.x;

    int r = tid >> 2, c0 = (tid & 3) * 16;
    size_t gin = (size_t)bi * L * H + (size_t)(s0 + r) * H + h0 + c0;
    unsigned short v[16];
    if (isbf) {
        const unsigned short* p = (const unsigned short*)src + gin;
        *(ushortx8*)&v[0] = *(const ushortx8*)p;
        *(ushortx8*)&v[8] = *(const ushortx8*)(p + 8);
    } else {
        const float* p = (const float*)src + gin;
#pragma unroll
        for (int u = 0; u < 16; u += 4) {
            float4 f = *(const float4*)(p + u);
            v[u] = f2bf(f.x); v[u + 1] = f2bf(f.y);
            v[u + 2] = f2bf(f.z); v[u + 3] = f2bf(f.w);
        }
    }
    *(ushortx8*)&T[r][c0] = *(const ushortx8*)&v[0];
    *(ushortx8*)&T[r][c0 + 8] = *(const ushortx8*)&v[8];
    if (!isbf) {
        size_t gco = (size_t)bi_l * L * H + (size_t)(s0 + r) * H + h0 + c0;
        *(ushortx8*)&xc[gco] = *(const ushortx8*)&v[0];
        *(ushortx8*)&xc[gco + 8] = *(const ushortx8*)&v[8];
    }
    __syncthreads();

    int hr = tid >> 2, sc0 = (tid & 3) * 16;
    unsigned short tv2[16];
    float ms = 0.f;
#pragma unroll
    for (int u = 0; u < 16; ++u) {
        unsigned short q = T[sc0 + u][hr];
        tv2[u] = q;
        ms += bf2f(q);
    }
    size_t gto = (size_t)bi_l * (size_t)H * L + (size_t)(h0 + hr) * L + s0 + sc0;
    *(ushortx8*)&xT[gto] = *(const ushortx8*)&tv2[0];
    *(ushortx8*)&xT[gto + 8] = *(const ushortx8*)&tv2[8];
    ms += __shfl_xor(ms, 1);
    ms += __shfl_xor(ms, 2);
    if ((tid & 3) == 0) atomicAdd(&msum[bi * H + h0 + hr], ms);
}

// 64x64 bf16 tile transpose: wT[t][s] = w[s][t]. grid (16,16,nb); block 256.
__global__ __launch_bounds__(256) void wtrans_kernel(const unsigned short* w,
                                                     unsigned short* wT) {
    __shared__ __align__(16) unsigned short T[64][80];
    int bi_l = blockIdx.z;
    int s0 = blockIdx.y * 64, t0 = blockIdx.x * 64;
    int tid = threadIdx.x;
    int r = tid >> 2, c0 = (tid & 3) * 16;
    size_t gin = (size_t)bi_l * L * L + (size_t)(s0 + r) * L + t0 + c0;
    *(ushortx8*)&T[r][c0] = *(const ushortx8*)&w[gin];
    *(ushortx8*)&T[r][c0 + 8] = *(const ushortx8*)&w[gin + 8];
    __syncthreads();
    int tr = tid >> 2, sc0 = (tid & 3) * 16;
    unsigned short o[16];
#pragma unroll
    for (int u = 0; u < 16; ++u) o[u] = T[sc0 + u][tr];
    size_t gout = (size_t)bi_l * L * L + (size_t)(t0 + tr) * L + s0 + sc0;
    *(ushortx8*)&wT[gout] = *(const ushortx8*)&o[0];
    *(ushortx8*)&wT[gout + 8] = *(const ushortx8*)&o[8];
}

// Stage one 128x32 A-tile + 128x32 B-tile into LDS with pre-swizzled SOURCE
// granule (rule #21: LDS dest must stay linear for global_load_lds; the
// 16B-granule permutation g ^= (row>>1)&3 is applied to the global address,
// and the identical XOR is applied on the ds_read side).
__device__ __forceinline__ void stage_tiles(
    const unsigned short* Arow, const unsigned short* Brow,
    int lda, int ldb, int k0,
    unsigned short* As, unsigned short* Bs, int tid) {
#pragma unroll
    for (int it = 0; it < 4; ++it) {
        int idx = (it & 1) * 256 + tid;       // 0..511
        int rr = idx >> 2;
        int gs = (idx & 3) ^ ((rr >> 1) & 3); // pre-swizzled source granule
        const unsigned short* src = (it < 2)
            ? (Arow + (size_t)rr * lda + k0 + gs * 8)
            : (Brow + (size_t)rr * ldb + k0 + gs * 8);
        unsigned short* dst = ((it < 2) ? As : Bs) + idx * 8;
        gload_lds16(src, dst);
    }
}

// Counted-vmcnt depth-3 triple-buffered K-loop (T3/T4-lite + T5 + swizzle).
// C(128x128) += A(128xK) * B(128xK)^T, K = 1024 fixed (NT = 32).
// Raw s_barrier (NOT __syncthreads: that drains vmcnt(0) -> the m97 stall).
// Steady state: stages t+1,t+2 in flight across tile t's compute (vmcnt(8)).
// Buf-overwrite race handled by lgkmcnt(0)+sched_barrier before 2nd barrier.
__device__ __forceinline__ void gemm_kk_pipe(
    const unsigned short* Arow, const unsigned short* Brow,
    int lda, int ldb,
    unsigned short* lds,    // 3 x 8192 u16: (As,Bs) triple-buffered, 48 KiB
    int tid, floatx4 (&acc)[4][4]) {
    const int NT = 32;
    int lane = tid & 63, wid = tid >> 6;
    int wm = wid >> 1, wn = wid & 1;
    int lane15 = lane & 15, quad = lane >> 4;
    int gsw = (quad ^ ((lane15 >> 1) & 3)) * 8;  // swizzled read granule (u16)

    stage_tiles(Arow, Brow, lda, ldb, 0,  lds,         lds + 4096,  tid);
    stage_tiles(Arow, Brow, lda, ldb, 32, lds + 8192,  lds + 12288, tid);
    stage_tiles(Arow, Brow, lda, ldb, 64, lds + 16384, lds + 20480, tid);

    int p = 0;
    for (int t = 0; t < NT; ++t) {
        unsigned short* As = lds + p * 8192;
        unsigned short* Bs = As + 4096;
        // wait for stage t; keep up to 2 later stages (8 loads/wave) flying
        if (t < NT - 2)      asm volatile("s_waitcnt vmcnt(8)" ::: "memory");
        else if (t == NT - 2) asm volatile("s_waitcnt vmcnt(4)" ::: "memory");
        else                 asm volatile("s_waitcnt vmcnt(0)" ::: "memory");
        __builtin_amdgcn_s_barrier();           // all waves' stage-t writes done
        asm volatile("" ::: "memory");          // no load hoists above barrier
        shortx8 af[4], bfr[4];
#pragma unroll
        for (int i = 0; i < 4; ++i)
            af[i] = *(const shortx8*)(As + (wm * 64 + i * 16 + lane15) * 32 + gsw);
#pragma unroll
        for (int j = 0; j < 4; ++j)
            bfr[j] = *(const shortx8*)(Bs + (wn * 64 + j * 16 + lane15) * 32 + gsw);
        asm volatile("s_waitcnt lgkmcnt(0)" ::: "memory");  // my reads complete
        __builtin_amdgcn_sched_barrier(0);
        __builtin_amdgcn_s_barrier();           // everyone's reads complete
        asm volatile("" ::: "memory");          // no stage hoists above barrier
        if (t + 3 < NT)                          // overwrite just-freed buf p
            stage_tiles(Arow, Brow, lda, ldb, (t + 3) * 32, As, Bs, tid);
        __builtin_amdgcn_s_setprio(1);
#pragma unroll
        for (int i = 0; i < 4; ++i)
#pragma unroll
            for (int j = 0; j < 4; ++j)
                acc[i][j] = __builtin_amdgcn_mfma_f32_16x16x32_bf16(af[i], bfr[j], acc[i][j], 0, 0, 0);
        __builtin_amdgcn_s_setprio(0);
        p = (p == 2) ? 0 : p + 1;
    }
    __builtin_amdgcn_s_barrier();
}

// S = a.b^T * tau; w = mask ? exp(S) : 0 (bf16). Fused row/col sums.
__global__ __launch_bounds__(256) void score_kernel(
    const void* Araw, const void* Braw,
    const unsigned short* a_c, const unsigned short* b_c,
    const int* mask_a, const int* mask_b, const void* temp, const int* flag,
    unsigned short* w, float* row_l, float* col_l, int b0, int nb) {
    __shared__ __align__(16) unsigned short lds[24576];   // 48 KiB: 3x dbuf
    int bi_l, tx, ty;
    swz_tile(nb, bi_l, tx, ty);
    int bi = b0 + bi_l;
    int s0 = ty * 128, t0 = tx * 128;
    int tid = threadIdx.x;
    int isbf = flag[0];

    floatx4 acc[4][4];
#pragma unroll
    for (int i = 0; i < 4; ++i)
#pragma unroll
        for (int j = 0; j < 4; ++j)
#pragma unroll
            for (int rr = 0; rr < 4; ++rr) acc[i][j][rr] = 0.f;

    const unsigned short* Arow = isbf
        ? (const unsigned short*)Araw + (size_t)bi * L * H + (size_t)s0 * H
        : a_c + (size_t)bi_l * L * H + (size_t)s0 * H;
    const unsigned short* Brow = isbf
        ? (const unsigned short*)Braw + (size_t)bi * L * H + (size_t)t0 * H
        : b_c + (size_t)bi_l * L * H + (size_t)t0 * H;
    gemm_kk_pipe(Arow, Brow, H, H, lds, tid, acc);

    float tv = isbf ? bf2f(((const unsigned short*)temp)[0]) : ((const float*)temp)[0];
    int lane = tid & 63, wid = tid >> 6;
    int wm = wid >> 1, wn = wid & 1;
    int lane15 = lane & 15, quad = lane >> 4;

    int mb[4];
#pragma unroll
    for (int j = 0; j < 4; ++j)
        mb[j] = mask_b[bi * L + t0 + wn * 64 + j * 16 + lane15];
    size_t wbase = (size_t)bi_l * L * L;
    float colp[4] = {0.f, 0.f, 0.f, 0.f};
#pragma unroll
    for (int i = 0; i < 4; ++i) {
#pragma unroll
        for (int r = 0; r < 4; ++r) {
            int s = s0 + wm * 64 + i * 16 + quad * 4 + r;
            int ma = mask_a[bi * L + s];
            float rp = 0.f;
#pragma unroll
            for (int j = 0; j < 4; ++j) {
                int t = t0 + wn * 64 + j * 16 + lane15;
                float wv = (ma && mb[j]) ? __expf(acc[i][j][r] * tv) : 0.f;
                unsigned short wq = f2bf(wv);
                w[wbase + (size_t)s * L + t] = wq;
                float wf = bf2f(wq);       // sum exactly what we stored
                rp += wf;
                colp[j] += wf;
            }
            rp += __shfl_xor(rp, 1);
            rp += __shfl_xor(rp, 2);
            rp += __shfl_xor(rp, 4);
            rp += __shfl_xor(rp, 8);
            if (lane15 == 0) atomicAdd(&row_l[bi * L + s], rp);
        }
    }
#pragma unroll
    for (int j = 0; j < 4; ++j) {
        float cp = colp[j];
        cp += __shfl_xor(cp, 16);
        cp += __shfl_xor(cp, 32);
        if (quad == 0) {
            int t = t0 + wn * 64 + j * 16 + lane15;
            atomicAdd(&col_l[bi * L + t], cp);
        }
    }
}

// feature_a[s,h] = ma ? (sum_t w[s,t] b[t,h]) / row_l[s] : mean_b[h]
__global__ __launch_bounds__(256) void feat_a_kernel(
    const unsigned short* w, const unsigned short* bT, const int* mask_a,
    const int* flag, const float* row_l, const float* mean_b, void* out,
    int b0, int nb) {
    __shared__ __align__(16) unsigned short lds[24576];
    int bi_l, tx, ty;
    swz_tile(nb, bi_l, tx, ty);
    int bi = b0 + bi_l;
    int s0 = ty * 128, h0 = tx * 128;
    int tid = threadIdx.x;

    floatx4 acc[4][4];
#pragma unroll
    for (int i = 0; i < 4; ++i)
#pragma unroll
        for (int j = 0; j < 4; ++j)
#pragma unroll
            for (int rr = 0; rr < 4; ++rr) acc[i][j][rr] = 0.f;

    gemm_kk_pipe(w + (size_t)bi_l * L * L + (size_t)s0 * L,
                 bT + (size_t)bi_l * (size_t)H * L + (size_t)h0 * L,
                 L, L, lds, tid, acc);

    int isbf = flag[0];
    int lane = tid & 63, wid = tid >> 6;
    int wm = wid >> 1, wn = wid & 1;
    int lane15 = lane & 15, quad = lane >> 4;
    const float invL = 1.f / (float)L;
#pragma unroll
    for (int i = 0; i < 4; ++i) {
#pragma unroll
        for (int r = 0; r < 4; ++r) {
            int s = s0 + wm * 64 + i * 16 + quad * 4 + r;
            int ma = mask_a[bi * L + s];
            float scale = ma ? (1.f / row_l[bi * L + s]) : 0.f;
#pragma unroll
            for (int j = 0; j < 4; ++j) {
                int h = h0 + wn * 64 + j * 16 + lane15;
                float v = ma ? acc[i][j][r] * scale : mean_b[bi * H + h] * invL;
                store_out(out, (size_t)bi * L * H + (size_t)s * H + h, v, isbf);
            }
        }
    }
}

// feature_b[t,h] = mb ? (sum_s w[s,t] a[s,h]) / col_l[t] : mean_a[h]
__global__ __launch_bounds__(256) void feat_b_kernel(
    const unsigned short* wT, const unsigned short* aT, const int* mask_b,
    const int* flag, const float* col_l, const float* mean_a, void* out,
    int b0, int nb) {
    __shared__ __align__(16) unsigned short lds[24576];
    int bi_l, tx, ty;
    swz_tile(nb, bi_l, tx, ty);
    int bi = b0 + bi_l;
    int t0 = ty * 128, h0 = tx * 128;
    int tid = threadIdx.x;

    floatx4 acc[4][4];
#pragma unroll
    for (int i = 0; i < 4; ++i)
#pragma unroll
        for (int j = 0; j < 4; ++j)
#pragma unroll
            for (int rr = 0; rr < 4; ++rr) acc[i][j][rr] = 0.f;

    gemm_kk_pipe(wT + (size_t)bi_l * L * L + (size_t)t0 * L,
                 aT + (size_t)bi_l * (size_t)H * L + (size_t)h0 * L,
                 L, L, lds, tid, acc);

    int isbf = flag[0];
    int lane = tid & 63, wid = tid >> 6;
    int wm = wid >> 1, wn = wid & 1;
    int lane15 = lane & 15, quad = lane >> 4;
    const float invL = 1.f / (float)L;
    const size_t FEAT_B_OFF = (size_t)NB * L * H;
#pragma unroll
    for (int i = 0; i < 4; ++i) {
#pragma unroll
        for (int r = 0; r < 4; ++r) {
            int t = t0 + wm * 64 + i * 16 + quad * 4 + r;
            int mbv = mask_b[bi * L + t];
            float scale = mbv ? (1.f / col_l[bi * L + t]) : 0.f;
#pragma unroll
            for (int j = 0; j < 4; ++j) {
                int h = h0 + wn * 64 + j * 16 + lane15;
                float v = mbv ? acc[i][j][r] * scale : mean_a[bi * H + h] * invL;
                store_out(out, FEAT_B_OFF + (size_t)bi * L * H + (size_t)t * H + h, v, isbf);
            }
        }
    }
}

extern "C" void kernel_launch(void* const* d_in, const int* in_sizes, int n_in,
                              void* d_out, int out_size, void* d_ws, size_t ws_size,
                              hipStream_t stream) {
    const void* a = d_in[0];
    const void* b = d_in[1];
    const int* mask_a = (const int*)d_in[2];
    const int* mask_b = (const int*)d_in[3];
    const void* temp = d_in[4];

    char* wsp = (char*)d_ws;
    float* row_l  = (float*)wsp;                       // NB*L
    float* col_l  = row_l + (size_t)NB * L;            // NB*L
    float* mean_a = col_l + (size_t)NB * L;            // NB*H (raw sums)
    float* mean_b = mean_a + (size_t)NB * H;           // NB*H (raw sums)
    int*   flag   = (int*)(mean_b + (size_t)NB * H);
    const size_t stats_bytes = ((size_t)NB * L * 2 + (size_t)NB * H * 2) * 4 + 256;

    const size_t per_batch = 6 * (size_t)L * H * 2;    // a_c,b_c,aT,bT,w,wT
    size_t wavail = (ws_size > stats_bytes) ? ws_size - stats_bytes : 0;
    int chunk = (int)(wavail / per_batch);
    if (chunk < 1) chunk = 1;
    if (chunk > NB) chunk = NB;

    unsigned short* a_c  = (unsigned short*)(wsp + stats_bytes);
    unsigned short* b_c  = a_c + (size_t)chunk * L * H;
    unsigned short* aT   = b_c + (size_t)chunk * L * H;
    unsigned short* bT   = aT  + (size_t)chunk * L * H;
    unsigned short* wbuf = bT  + (size_t)chunk * L * H;
    unsigned short* wT   = wbuf + (size_t)chunk * L * L;

    hipMemsetAsync(d_ws, 0, stats_bytes, stream);      // zero row/col/mean accums
    detect_kernel<<<1, 64, 0, stream>>>((const unsigned short*)a, flag);

    for (int b0 = 0; b0 < NB; b0 += chunk) {
        int nb = (NB - b0 < chunk) ? (NB - b0) : chunk;
        convT_kernel<<<dim3(16, 16, nb * 2), 256, 0, stream>>>(
            a, b, flag, a_c, b_c, aT, bT, mean_a, mean_b, b0);
        score_kernel<<<dim3(nb * 64), 256, 0, stream>>>(
            a, b, a_c, b_c, mask_a, mask_b, temp, flag, wbuf,
            row_l, col_l, b0, nb);
        wtrans_kernel<<<dim3(16, 16, nb), 256, 0, stream>>>(wbuf, wT);
        feat_a_kernel<<<dim3(nb * 64), 256, 0, stream>>>(
            wbuf, bT, mask_a, flag, row_l, mean_b, d_out, b0, nb);
        feat_b_kernel<<<dim3(nb * 64), 256, 0, stream>>>(
            wT, aT, mask_b, flag, col_l, mean_a, d_out, b0, nb);
    }
}

// Round 6
// 820.486 us; speedup vs baseline: 1.1181x; 1.0629x over previous
//
#include <hip/hip_runtime.h>

#define NB 32
#define L 1024
#define H 1024

typedef __attribute__((ext_vector_type(4))) float floatx4;
typedef __attribute__((ext_vector_type(8))) short shortx8;
typedef __attribute__((ext_vector_type(8))) unsigned short ushortx8;

__device__ __forceinline__ unsigned short f2bf(float f) {
    union { float f; unsigned int u; } v; v.f = f;
    unsigned int u = v.u;
    u += 0x7fffu + ((u >> 16) & 1u);   // round-to-nearest-even
    return (unsigned short)(u >> 16);
}
__device__ __forceinline__ float bf2f(unsigned short h) {
    union { unsigned int u; float f; } v; v.u = ((unsigned int)h) << 16;
    return v.f;
}

// async global->LDS, 16B per lane. Dest must be wave-uniform base + lane*16.
__device__ __forceinline__ void gload_lds16(const void* g, void* l) {
    __builtin_amdgcn_global_load_lds(
        (const __attribute__((address_space(1))) unsigned int*)g,
        (__attribute__((address_space(3))) unsigned int*)l, 16, 0, 0);
}

// T1: XCD batch-chunk swizzle for the 256^2 GEMM grid (nwg = nb*16, %8==0).
__device__ __forceinline__ void swz256(int nb, int& bi_l, int& tx, int& ty) {
    int fid = blockIdx.x;
    int wid = (fid & 7) * (nb * 2) + (fid >> 3);
    bi_l = wid >> 4;
    int t = wid & 15;
    tx = t & 3;
    ty = t >> 2;
}

// ---- dtype detection: bf16 vs fp32 materialization of the float tensors ----
__global__ void detect_kernel(const unsigned short* a, int* flag) {
    int tid = threadIdx.x;
    unsigned short u = a[tid];
    int e = (u >> 7) & 0xff;
    int ok = (u == 0) || (e >= 116 && e <= 136);
    unsigned long long ball = __ballot(ok != 0);
    if (tid == 0) flag[0] = (__popcll(ball) >= 56) ? 1 : 0;
}

__device__ __forceinline__ void store_out(void* out, size_t eidx, float v, int isbf) {
    if (isbf) ((unsigned short*)out)[eidx] = f2bf(v);
    else      ((float*)out)[eidx] = v;
}

// Produce bf16 transposes aT/bT (+ per-(b,h) sums for means). fp32 path also
// materializes contiguous bf16 a_c/b_c. grid: (H/64, L/64, nb*2); block 256.
__global__ __launch_bounds__(256) void convT_kernel(
    const void* A, const void* Bm, const int* flag,
    unsigned short* a_c, unsigned short* b_c,
    unsigned short* aT, unsigned short* bT,
    float* mean_a, float* mean_b, int b0) {
    __shared__ __align__(16) unsigned short T[64][80];
    int z = blockIdx.z;
    int which = z & 1, bi_l = z >> 1, bi = b0 + bi_l;
    int s0 = blockIdx.y * 64, h0 = blockIdx.x * 64;
    const void* src = which ? Bm : A;
    unsigned short* xc = which ? b_c : a_c;
    unsigned short* xT = which ? bT : aT;
    float* msum = which ? mean_b : mean_a;
    int isbf = flag[0];
    int tid = threadIdx.x;

    int r = tid >> 2, c0 = (tid & 3) * 16;
    size_t gin = (size_t)bi * L * H + (size_t)(s0 + r) * H + h0 + c0;
    unsigned short v[16];
    if (isbf) {
        const unsigned short* p = (const unsigned short*)src + gin;
        *(ushortx8*)&v[0] = *(const ushortx8*)p;
        *(ushortx8*)&v[8] = *(const ushortx8*)(p + 8);
    } else {
        const float* p = (const float*)src + gin;
#pragma unroll
        for (int u = 0; u < 16; u += 4) {
            float4 f = *(const float4*)(p + u);
            v[u] = f2bf(f.x); v[u + 1] = f2bf(f.y);
            v[u + 2] = f2bf(f.z); v[u + 3] = f2bf(f.w);
        }
    }
    *(ushortx8*)&T[r][c0] = *(const ushortx8*)&v[0];
    *(ushortx8*)&T[r][c0 + 8] = *(const ushortx8*)&v[8];
    if (!isbf) {
        size_t gco = (size_t)bi_l * L * H + (size_t)(s0 + r) * H + h0 + c0;
        *(ushortx8*)&xc[gco] = *(const ushortx8*)&v[0];
        *(ushortx8*)&xc[gco + 8] = *(const ushortx8*)&v[8];
    }
    __syncthreads();

    int hr = tid >> 2, sc0 = (tid & 3) * 16;
    unsigned short tv2[16];
    float ms = 0.f;
#pragma unroll
    for (int u = 0; u < 16; ++u) {
        unsigned short q = T[sc0 + u][hr];
        tv2[u] = q;
        ms += bf2f(q);
    }
    size_t gto = (size_t)bi_l * (size_t)H * L + (size_t)(h0 + hr) * L + s0 + sc0;
    *(ushortx8*)&xT[gto] = *(const ushortx8*)&tv2[0];
    *(ushortx8*)&xT[gto + 8] = *(const ushortx8*)&tv2[8];
    ms += __shfl_xor(ms, 1);
    ms += __shfl_xor(ms, 2);
    if ((tid & 3) == 0) atomicAdd(&msum[bi * H + h0 + hr], ms);
}

// 64x64 bf16 tile transpose: wT[t][s] = w[s][t]. grid (16,16,nb); block 256.
__global__ __launch_bounds__(256) void wtrans_kernel(const unsigned short* w,
                                                     unsigned short* wT) {
    __shared__ __align__(16) unsigned short T[64][80];
    int bi_l = blockIdx.z;
    int s0 = blockIdx.y * 64, t0 = blockIdx.x * 64;
    int tid = threadIdx.x;
    int r = tid >> 2, c0 = (tid & 3) * 16;
    size_t gin = (size_t)bi_l * L * L + (size_t)(s0 + r) * L + t0 + c0;
    *(ushortx8*)&T[r][c0] = *(const ushortx8*)&w[gin];
    *(ushortx8*)&T[r][c0 + 8] = *(const ushortx8*)&w[gin + 8];
    __syncthreads();
    int tr = tid >> 2, sc0 = (tid & 3) * 16;
    unsigned short o[16];
#pragma unroll
    for (int u = 0; u < 16; ++u) o[u] = T[sc0 + u][tr];
    size_t gout = (size_t)bi_l * L * L + (size_t)(t0 + tr) * L + s0 + sc0;
    *(ushortx8*)&wT[gout] = *(const ushortx8*)&o[0];
    *(ushortx8*)&wT[gout + 8] = *(const ushortx8*)&o[8];
}

// ---- 256x256 / BK=64 minimal-2-phase GEMM (T3 recipe, T1+T5, src-swizzle) ----
// Stage a 256x64 A-tile + 256x64 B-tile into LDS. 8 gload_lds per thread.
// 16B granule g within each row is stored from global granule g^(row&7); the
// ds_read side applies the same XOR (both-sides involution, rule #21) so
// fragment reads (16 rows @ same column) spread across all 8 bank-slots.
__device__ __forceinline__ void stage256(
    const unsigned short* Arow, const unsigned short* Brow, int k0,
    unsigned short* As, unsigned short* Bs, int tid) {
#pragma unroll
    for (int l = 0; l < 4; ++l) {
        int idx = l * 512 + tid;              // 0..2047
        int row = idx >> 3;
        int g = (idx & 7) ^ (row & 7);
        gload_lds16(Arow + (size_t)row * 1024 + k0 + g * 8, As + idx * 8);
    }
#pragma unroll
    for (int l = 0; l < 4; ++l) {
        int idx = l * 512 + tid;
        int row = idx >> 3;
        int g = (idx & 7) ^ (row & 7);
        gload_lds16(Brow + (size_t)row * 1024 + k0 + g * 8, Bs + idx * 8);
    }
}

// C(256x256) += A(256x1024) * B(256x1024)^T, both operands k-contiguous bf16,
// stride 1024. 8 waves: wm = wid>>2 (2), wn = wid&3 (4); per-wave 128x64 out.
// One vmcnt(0)+s_barrier per K-step (16 steps); STAGE(next) issued BEFORE the
// compute so the loads fly under ds_read+MFMA (catalog T3 minimal recipe).
__device__ __forceinline__ void gemm256_pipe(
    const unsigned short* Arow, const unsigned short* Brow,
    unsigned short* lds,   // 65536 u16 = 128 KiB: [A0|B0|A1|B1] x 16384
    int tid, floatx4 (&acc)[8][4]) {
    const int NT = 16;
    int lane = tid & 63, wid = tid >> 6;
    int wm = wid >> 2, wn = wid & 3;
    int lane15 = lane & 15, quad = lane >> 4;
    int l7 = lane15 & 7;

    stage256(Arow, Brow, 0, lds, lds + 16384, tid);
    asm volatile("s_waitcnt vmcnt(0)" ::: "memory");
    __builtin_amdgcn_s_barrier();
    asm volatile("" ::: "memory");

    for (int t = 0; t < NT; ++t) {
        unsigned short* cur = lds + (t & 1) * 32768;
        unsigned short* nxt = lds + ((t & 1) ^ 1) * 32768;
        if (t + 1 < NT)   // buf nxt fully read last step (published by barrier)
            stage256(Arow, Brow, (t + 1) * 64, nxt, nxt + 16384, tid);
#pragma unroll
        for (int ks = 0; ks < 2; ++ks) {
            shortx8 af[8], bf[4];
#pragma unroll
            for (int m = 0; m < 8; ++m) {
                int row = wm * 128 + m * 16 + lane15;
                int col = (ks * 4 + quad) ^ l7;
                af[m] = *(const shortx8*)(cur + row * 64 + col * 8);
            }
#pragma unroll
            for (int n = 0; n < 4; ++n) {
                int row = wn * 64 + n * 16 + lane15;
                int col = (ks * 4 + quad) ^ l7;
                bf[n] = *(const shortx8*)(cur + 16384 + row * 64 + col * 8);
            }
            asm volatile("s_waitcnt lgkmcnt(0)" ::: "memory");
            __builtin_amdgcn_sched_barrier(0);
            __builtin_amdgcn_s_setprio(1);
#pragma unroll
            for (int m = 0; m < 8; ++m)
#pragma unroll
                for (int n = 0; n < 4; ++n)
                    acc[m][n] = __builtin_amdgcn_mfma_f32_16x16x32_bf16(
                        af[m], bf[n], acc[m][n], 0, 0, 0);
            __builtin_amdgcn_s_setprio(0);
        }
        asm volatile("s_waitcnt vmcnt(0)" ::: "memory");  // nxt's stage landed
        __builtin_amdgcn_s_barrier();   // all waves done reading cur + see nxt
        asm volatile("" ::: "memory");
    }
}

// S = a.b^T * tau; w = mask ? exp(S) : 0 (bf16). Fused row/col sums.
__global__ __launch_bounds__(512, 2) void score_kernel(
    const void* Araw, const void* Braw,
    const unsigned short* a_c, const unsigned short* b_c,
    const int* mask_a, const int* mask_b, const void* temp, const int* flag,
    unsigned short* w, float* row_l, float* col_l, int b0, int nb) {
    __shared__ __align__(16) unsigned short lds[65536];   // 128 KiB dbuf
    int bi_l, tx, ty;
    swz256(nb, bi_l, tx, ty);
    int bi = b0 + bi_l;
    int s0 = ty * 256, t0 = tx * 256;
    int tid = threadIdx.x;
    int isbf = flag[0];

    floatx4 acc[8][4];
#pragma unroll
    for (int m = 0; m < 8; ++m)
#pragma unroll
        for (int n = 0; n < 4; ++n)
#pragma unroll
            for (int rr = 0; rr < 4; ++rr) acc[m][n][rr] = 0.f;

    const unsigned short* Arow = isbf
        ? (const unsigned short*)Araw + (size_t)bi * L * H + (size_t)s0 * H
        : a_c + (size_t)bi_l * L * H + (size_t)s0 * H;
    const unsigned short* Brow = isbf
        ? (const unsigned short*)Braw + (size_t)bi * L * H + (size_t)t0 * H
        : b_c + (size_t)bi_l * L * H + (size_t)t0 * H;
    gemm256_pipe(Arow, Brow, lds, tid, acc);

    float tv = isbf ? bf2f(((const unsigned short*)temp)[0]) : ((const float*)temp)[0];
    int lane = tid & 63, wid = tid >> 6;
    int wm = wid >> 2, wn = wid & 3;
    int lane15 = lane & 15, quad = lane >> 4;

    int mbv[4];
#pragma unroll
    for (int n = 0; n < 4; ++n)
        mbv[n] = mask_b[bi * L + t0 + wn * 64 + n * 16 + lane15];
    size_t wbase = (size_t)bi_l * L * L;
    float colp[4] = {0.f, 0.f, 0.f, 0.f};
#pragma unroll
    for (int m = 0; m < 8; ++m) {
#pragma unroll
        for (int r = 0; r < 4; ++r) {
            int s = s0 + wm * 128 + m * 16 + quad * 4 + r;
            int ma = mask_a[bi * L + s];
            float rp = 0.f;
#pragma unroll
            for (int n = 0; n < 4; ++n) {
                int t = t0 + wn * 64 + n * 16 + lane15;
                float wv = (ma && mbv[n]) ? __expf(acc[m][n][r] * tv) : 0.f;
                unsigned short wq = f2bf(wv);
                w[wbase + (size_t)s * L + t] = wq;
                float wf = bf2f(wq);       // sum exactly what we stored
                rp += wf;
                colp[n] += wf;
            }
            rp += __shfl_xor(rp, 1);
            rp += __shfl_xor(rp, 2);
            rp += __shfl_xor(rp, 4);
            rp += __shfl_xor(rp, 8);
            if (lane15 == 0) atomicAdd(&row_l[bi * L + s], rp);
        }
    }
#pragma unroll
    for (int n = 0; n < 4; ++n) {
        float cp = colp[n];
        cp += __shfl_xor(cp, 16);
        cp += __shfl_xor(cp, 32);
        if (quad == 0) {
            int t = t0 + wn * 64 + n * 16 + lane15;
            atomicAdd(&col_l[bi * L + t], cp);
        }
    }
}

// feature_a[s,h] = ma ? (sum_t w[s,t] b[t,h]) / row_l[s] : mean_b[h]
__global__ __launch_bounds__(512, 2) void feat_a_kernel(
    const unsigned short* w, const unsigned short* bT, const int* mask_a,
    const int* flag, const float* row_l, const float* mean_b, void* out,
    int b0, int nb) {
    __shared__ __align__(16) unsigned short lds[65536];
    int bi_l, tx, ty;
    swz256(nb, bi_l, tx, ty);
    int bi = b0 + bi_l;
    int s0 = ty * 256, h0 = tx * 256;
    int tid = threadIdx.x;

    floatx4 acc[8][4];
#pragma unroll
    for (int m = 0; m < 8; ++m)
#pragma unroll
        for (int n = 0; n < 4; ++n)
#pragma unroll
            for (int rr = 0; rr < 4; ++rr) acc[m][n][rr] = 0.f;

    gemm256_pipe(w + (size_t)bi_l * L * L + (size_t)s0 * L,
                 bT + (size_t)bi_l * (size_t)H * L + (size_t)h0 * L,
                 lds, tid, acc);

    int isbf = flag[0];
    int lane = tid & 63, wid = tid >> 6;
    int wm = wid >> 2, wn = wid & 3;
    int lane15 = lane & 15, quad = lane >> 4;
    const float invL = 1.f / (float)L;
#pragma unroll
    for (int m = 0; m < 8; ++m) {
#pragma unroll
        for (int r = 0; r < 4; ++r) {
            int s = s0 + wm * 128 + m * 16 + quad * 4 + r;
            int ma = mask_a[bi * L + s];
            float scale = ma ? (1.f / row_l[bi * L + s]) : 0.f;
#pragma unroll
            for (int n = 0; n < 4; ++n) {
                int h = h0 + wn * 64 + n * 16 + lane15;
                float v = ma ? acc[m][n][r] * scale : mean_b[bi * H + h] * invL;
                store_out(out, (size_t)bi * L * H + (size_t)s * H + h, v, isbf);
            }
        }
    }
}

// feature_b[t,h] = mb ? (sum_s w[s,t] a[s,h]) / col_l[t] : mean_a[h]
__global__ __launch_bounds__(512, 2) void feat_b_kernel(
    const unsigned short* wT, const unsigned short* aT, const int* mask_b,
    const int* flag, const float* col_l, const float* mean_a, void* out,
    int b0, int nb) {
    __shared__ __align__(16) unsigned short lds[65536];
    int bi_l, tx, ty;
    swz256(nb, bi_l, tx, ty);
    int bi = b0 + bi_l;
    int t0 = ty * 256, h0 = tx * 256;
    int tid = threadIdx.x;

    floatx4 acc[8][4];
#pragma unroll
    for (int m = 0; m < 8; ++m)
#pragma unroll
        for (int n = 0; n < 4; ++n)
#pragma unroll
            for (int rr = 0; rr < 4; ++rr) acc[m][n][rr] = 0.f;

    gemm256_pipe(wT + (size_t)bi_l * L * L + (size_t)t0 * L,
                 aT + (size_t)bi_l * (size_t)H * L + (size_t)h0 * L,
                 lds, tid, acc);

    int isbf = flag[0];
    int lane = tid & 63, wid = tid >> 6;
    int wm = wid >> 2, wn = wid & 3;
    int lane15 = lane & 15, quad = lane >> 4;
    const float invL = 1.f / (float)L;
    const size_t FEAT_B_OFF = (size_t)NB * L * H;
#pragma unroll
    for (int m = 0; m < 8; ++m) {
#pragma unroll
        for (int r = 0; r < 4; ++r) {
            int t = t0 + wm * 128 + m * 16 + quad * 4 + r;
            int mv = mask_b[bi * L + t];
            float scale = mv ? (1.f / col_l[bi * L + t]) : 0.f;
#pragma unroll
            for (int n = 0; n < 4; ++n) {
                int h = h0 + wn * 64 + n * 16 + lane15;
                float v = mv ? acc[m][n][r] * scale : mean_a[bi * H + h] * invL;
                store_out(out, FEAT_B_OFF + (size_t)bi * L * H + (size_t)t * H + h, v, isbf);
            }
        }
    }
}

extern "C" void kernel_launch(void* const* d_in, const int* in_sizes, int n_in,
                              void* d_out, int out_size, void* d_ws, size_t ws_size,
                              hipStream_t stream) {
    const void* a = d_in[0];
    const void* b = d_in[1];
    const int* mask_a = (const int*)d_in[2];
    const int* mask_b = (const int*)d_in[3];
    const void* temp = d_in[4];

    char* wsp = (char*)d_ws;
    float* row_l  = (float*)wsp;                       // NB*L
    float* col_l  = row_l + (size_t)NB * L;            // NB*L
    float* mean_a = col_l + (size_t)NB * L;            // NB*H (raw sums)
    float* mean_b = mean_a + (size_t)NB * H;           // NB*H (raw sums)
    int*   flag   = (int*)(mean_b + (size_t)NB * H);
    const size_t stats_bytes = ((size_t)NB * L * 2 + (size_t)NB * H * 2) * 4 + 256;

    const size_t per_batch = 6 * (size_t)L * H * 2;    // a_c,b_c,aT,bT,w,wT
    size_t wavail = (ws_size > stats_bytes) ? ws_size - stats_bytes : 0;
    int chunk = (int)(wavail / per_batch);
    if (chunk < 1) chunk = 1;
    if (chunk > NB) chunk = NB;

    unsigned short* a_c  = (unsigned short*)(wsp + stats_bytes);
    unsigned short* b_c  = a_c + (size_t)chunk * L * H;
    unsigned short* aT   = b_c + (size_t)chunk * L * H;
    unsigned short* bT   = aT  + (size_t)chunk * L * H;
    unsigned short* wbuf = bT  + (size_t)chunk * L * H;
    unsigned short* wT   = wbuf + (size_t)chunk * L * L;

    hipMemsetAsync(d_ws, 0, stats_bytes, stream);      // zero row/col/mean accums
    detect_kernel<<<1, 64, 0, stream>>>((const unsigned short*)a, flag);

    for (int b0 = 0; b0 < NB; b0 += chunk) {
        int nb = (NB - b0 < chunk) ? (NB - b0) : chunk;
        convT_kernel<<<dim3(16, 16, nb * 2), 256, 0, stream>>>(
            a, b, flag, a_c, b_c, aT, bT, mean_a, mean_b, b0);
        score_kernel<<<dim3(nb * 16), 512, 0, stream>>>(
            a, b, a_c, b_c, mask_a, mask_b, temp, flag, wbuf,
            row_l, col_l, b0, nb);
        wtrans_kernel<<<dim3(16, 16, nb), 256, 0, stream>>>(wbuf, wT);
        feat_a_kernel<<<dim3(nb * 16), 512, 0, stream>>>(
            wbuf, bT, mask_a, flag, row_l, mean_b, d_out, b0, nb);
        feat_b_kernel<<<dim3(nb * 16), 512, 0, stream>>>(
            wT, aT, mask_b, flag, col_l, mean_a, d_out, b0, nb);
    }
}